// Round 8
// baseline (1090.275 us; speedup 1.0000x reference)
//
#include <hip/hip_runtime.h>
#include <hip/hip_bf16.h>
#include <math.h>

#define N_NODES 50000
#define E0      800000
#define E_TOT   (E0 + N_NODES)

using bf16 = __hip_bfloat16;

static __device__ __forceinline__ float bfu2f_lo(unsigned u){ return __uint_as_float(u << 16); }
static __device__ __forceinline__ float bfu2f_hi(unsigned u){ return __uint_as_float(u & 0xffff0000u); }

// ---------------- dtype autodetect ----------------
// flag[0]=1 -> edges int32 ; flag[1]=1 -> float tensors are fp32
__global__ void k_detect(const int* __restrict__ ei, const unsigned* __restrict__ xu,
                         int* __restrict__ flag){
    __shared__ int e32, f32;
    if (threadIdx.x == 0){ e32 = 0; f32 = 0; }
    __syncthreads();
    if (ei[2 * threadIdx.x + 1] != 0) e32 = 1;        // int64 high words are 0
    if (threadIdx.x < 128){
        unsigned ex = (xu[threadIdx.x] >> 7) & 0xFF;  // bf16 exponent of low halfword
        if (ex < 100 || ex > 140) f32 = 1;            // fp32 mantissa bits look random
    }
    __syncthreads();
    if (threadIdx.x == 0){ flag[0] = e32; flag[1] = f32; }
}

static __device__ __forceinline__ float ldany(const void* p, int i, int isf32){
    return isf32 ? ((const float*)p)[i] : __bfloat162float(((const bf16*)p)[i]);
}

// vecf layout: b1 @0(128), bg @128(64), b3 @192(64), att_s @256(128), att_d @384(128)
__global__ void k_convert(const int* __restrict__ flag,
                          const void* W1, const void* Wg, const void* W3,
                          const void* b1, const void* bg, const void* b3,
                          const void* as_, const void* ad_,
                          float* __restrict__ W1f, float* __restrict__ Wgf,
                          float* __restrict__ W3f, float* __restrict__ vecf){
    int isf = flag[1];
    int b = blockIdx.x, t = threadIdx.x;
    if (b < 64){                 int i = b * 256 + t;         W1f[i] = ldany(W1, i, isf); }
    else if (b < 128){           int i = (b - 64) * 256 + t;  Wgf[i] = ldany(Wg, i, isf); }
    else if (b < 144){           int i = (b - 128) * 256 + t; W3f[i] = ldany(W3, i, isf); }
    else {
        int i = (b - 144) * 256 + t;     // 0..511
        float v;
        if      (i < 128) v = ldany(b1,  i,       isf);
        else if (i < 192) v = ldany(bg,  i - 128, isf);
        else if (i < 256) v = ldany(b3,  i - 192, isf);
        else if (i < 384) v = ldany(as_, i - 256, isf);
        else              v = ldany(ad_, i - 384, isf);
        vecf[i] = v;
    }
}

// x (N,128) -> bf16 copy
__global__ void k_convx(const void* __restrict__ xv, const int* __restrict__ flag,
                        bf16* __restrict__ xb){
    int i = blockIdx.x * 256 + threadIdx.x;
    if (i >= N_NODES * 128) return;
    xb[i] = __float2bfloat16(ldany(xv, i, flag[1]));
}

// ---------------- CSR build ----------------

__global__ void k_zero2(int* p0, int* p1, int n){
    int i = blockIdx.x * blockDim.x + threadIdx.x;
    if (i < n){ p0[i] = 0; p1[i] = 0; }
}

static __device__ __forceinline__ int load_dst(const int* ei, int e, int is32){
    if (e >= E0) return e - E0;
    return is32 ? ei[E0 + e] : (int)((const long long*)ei)[E0 + e];
}
static __device__ __forceinline__ int load_src(const int* ei, int e, int is32){
    if (e >= E0) return e - E0;
    return is32 ? ei[e] : (int)((const long long*)ei)[e];
}

__global__ void k_count(const int* __restrict__ ei, const int* __restrict__ flag,
                        int* __restrict__ deg){
    int e = blockIdx.x * blockDim.x + threadIdx.x;
    if (e >= E_TOT) return;
    int is32 = flag[0];
    int dst = load_dst(ei, e, is32);
    int src = load_src(ei, e, is32);
    if ((unsigned)dst >= N_NODES || (unsigned)src >= N_NODES) return;
    atomicAdd(&deg[dst], 1);
}

__global__ void k_scanA(const int* __restrict__ deg, int* __restrict__ tmp, int* __restrict__ blk){
    __shared__ int s[256];
    int t = threadIdx.x;
    int i = blockIdx.x * 256 + t;
    int v = (i < N_NODES) ? deg[i] : 0;
    s[t] = v; __syncthreads();
    for (int off = 1; off < 256; off <<= 1){
        int x = (t >= off) ? s[t - off] : 0;
        __syncthreads();
        s[t] += x;
        __syncthreads();
    }
    if (t == 255) blk[blockIdx.x] = s[255];
    if (i < N_NODES) tmp[i] = s[t] - v;
}

__global__ void k_scanB(int* __restrict__ blk, int nb){
    __shared__ int s[256];
    int t = threadIdx.x;
    int v = (t < nb) ? blk[t] : 0;
    s[t] = v; __syncthreads();
    for (int off = 1; off < 256; off <<= 1){
        int x = (t >= off) ? s[t - off] : 0;
        __syncthreads();
        s[t] += x;
        __syncthreads();
    }
    if (t < nb) blk[t] = s[t] - v;
}

__global__ void k_scanC(int* __restrict__ row_ptr, const int* __restrict__ blk,
                        const int* __restrict__ deg, float* __restrict__ inv_sqrt){
    int i = blockIdx.x * blockDim.x + threadIdx.x;
    if (i < N_NODES){
        row_ptr[i] += blk[i >> 8];
        int d = deg[i];
        inv_sqrt[i] = (d > 0) ? rsqrtf((float)d) : 0.0f;
    }
    if (i == 0) row_ptr[N_NODES] = E_TOT;
}

// also writes coef[pos] = isq[dst]*isq[src]
__global__ void k_fill(const int* __restrict__ ei, const int* __restrict__ flag,
                       const int* __restrict__ row_ptr, const float* __restrict__ isq,
                       int* __restrict__ cursor, int* __restrict__ csr_src,
                       float* __restrict__ coef){
    int e = blockIdx.x * blockDim.x + threadIdx.x;
    if (e >= E_TOT) return;
    int is32 = flag[0];
    int dst = load_dst(ei, e, is32);
    int src = load_src(ei, e, is32);
    if ((unsigned)dst >= N_NODES || (unsigned)src >= N_NODES) return;
    int pos = row_ptr[dst] + atomicAdd(&cursor[dst], 1);
    csr_src[pos] = src;
    coef[pos] = isq[dst] * isq[src];
}

// ---------------- mega1: gather(xb) -> GEMM1+ReLU -> GEMM2 -> att logits ----------------
// 256 threads (4 waves), 8 nodes/block. GATHER is node-per-wave: wave w handles
// nodes n0+2w, n0+2w+1; lane covers features (2f,2f+1) via one ushort2 load/edge.
// GEMM: thread (g=tid>>7, j=tid&127) owns rows 4g..4g+3, column j.
// X2 stored interleaved: row n, bf16 slot (f*2 + head) so k_gat reads one u32/lane.
__global__ __launch_bounds__(256) void k_mega1(
        const ushort2* __restrict__ xb2, const int* __restrict__ rp,
        const int* __restrict__ csr, const float* __restrict__ cf,
        const float* __restrict__ W1f, const float* __restrict__ Wgf,
        const float* __restrict__ vecf,
        bf16* __restrict__ X2, float* __restrict__ a_src, float* __restrict__ a_dst){
    __shared__ float as[8][128];
    __shared__ float hs[8][128];
    int n0 = blockIdx.x * 8;
    int w    = threadIdx.x >> 6;
    int lane = threadIdx.x & 63;

    // gather A_hat x: 2 sequential node-loops per wave, all 4 waves independent
    #pragma unroll
    for (int q = 0; q < 2; ++q){
        int r = 2 * w + q;
        int n = n0 + r;
        float a0 = 0.f, a1 = 0.f;
        int b = rp[n], e = rp[n + 1];
        for (int i = b; i < e; ++i){
            int s = csr[i];
            float c = cf[i];
            ushort2 v = xb2[(size_t)s * 64 + lane];
            a0 += c * __uint_as_float((unsigned)v.x << 16);
            a1 += c * __uint_as_float((unsigned)v.y << 16);
        }
        as[r][lane * 2]     = a0;
        as[r][lane * 2 + 1] = a1;
    }
    __syncthreads();

    int g = threadIdx.x >> 7, j = threadIdx.x & 127;
    // GEMM1 + b1 + ReLU (LDS float4 broadcasts, k unroll 4)
    {
        float acc[4] = {0.f, 0.f, 0.f, 0.f};
        for (int k = 0; k < 128; k += 4){
            float w0 = W1f[k * 128 + j],       w1 = W1f[(k + 1) * 128 + j];
            float w2 = W1f[(k + 2) * 128 + j], w3 = W1f[(k + 3) * 128 + j];
            #pragma unroll
            for (int r = 0; r < 4; ++r){
                float4 av = *(const float4*)&as[4 * g + r][k];
                acc[r] += av.x * w0 + av.y * w1 + av.z * w2 + av.w * w3;
            }
        }
        float bb = vecf[j];   // b1
        #pragma unroll
        for (int r = 0; r < 4; ++r) hs[4 * g + r][j] = fmaxf(acc[r] + bb, 0.f);
    }
    __syncthreads();

    // GEMM2 (h2 = h @ Wg) + att logits + interleaved bf16 store
    float acc2[4] = {0.f, 0.f, 0.f, 0.f};
    for (int k = 0; k < 128; k += 4){
        float w0 = Wgf[k * 128 + j],       w1 = Wgf[(k + 1) * 128 + j];
        float w2 = Wgf[(k + 2) * 128 + j], w3 = Wgf[(k + 3) * 128 + j];
        #pragma unroll
        for (int r = 0; r < 4; ++r){
            float4 av = *(const float4*)&hs[4 * g + r][k];
            acc2[r] += av.x * w0 + av.y * w1 + av.z * w2 + av.w * w3;
        }
    }
    float asv = vecf[256 + j], adv = vecf[384 + j];  // att_src, att_dst (head-major)
    int f = j & 63, h = j >> 6;                      // wave = g*2+h holds head h's 64 feats
    #pragma unroll
    for (int r = 0; r < 4; ++r){
        int n = n0 + 4 * g + r;
        X2[(size_t)n * 128 + f * 2 + h] = __float2bfloat16(acc2[r]);
        float ps = acc2[r] * asv, pd = acc2[r] * adv;
        for (int off = 32; off; off >>= 1){
            ps += __shfl_down(ps, off, 64);
            pd += __shfl_down(pd, off, 64);
        }
        if (f == 0){
            a_src[n * 2 + h] = ps;
            a_dst[n * 2 + h] = pd;
        }
    }
}

// ---------------- GAT aggregate: softmax (no-max; logits bounded) + mean + bg + ELU ----
__global__ __launch_bounds__(256) void k_gat(
        const unsigned* __restrict__ X2u, const int* __restrict__ rp,
        const int* __restrict__ csr, const float2* __restrict__ a_src,
        const float2* __restrict__ a_dst, const float* __restrict__ vecf,
        bf16* __restrict__ Y){
    int n = blockIdx.x * 4 + (threadIdx.x >> 6);
    int f = threadIdx.x & 63;
    float2 ad = a_dst[n];
    float l0 = 0.f, l1 = 0.f, o0 = 0.f, o1 = 0.f;
    int b = rp[n], e = rp[n + 1];
    for (int i = b; i < e; ++i){
        int s = csr[i];
        float2 av = a_src[s];
        unsigned v = X2u[(size_t)s * 64 + f];          // both heads, one 4B load
        float e0 = av.x + ad.x, e1 = av.y + ad.y;
        e0 = (e0 > 0.f) ? e0 : 0.2f * e0;              // leaky_relu 0.2
        e1 = (e1 > 0.f) ? e1 : 0.2f * e1;
        float p0 = __expf(e0), p1 = __expf(e1);
        l0 += p0;  o0 += p0 * bfu2f_lo(v);
        l1 += p1;  o1 += p1 * bfu2f_hi(v);
    }
    float val = 0.5f * (o0 / l0 + o1 / l1) + vecf[128 + f];  // bg (self-loop => l>0)
    val = (val > 0.f) ? val : expm1f(val);                    // ELU alpha=1
    Y[(size_t)n * 64 + f] = __float2bfloat16(val);
}

// ---------------- mega3: gather(Y bf16) + W3 GEMM (W3 in LDS) -> out ----------------
__global__ __launch_bounds__(256) void k_mega3(
        const bf16* __restrict__ Yb, const int* __restrict__ rp,
        const int* __restrict__ csr, const float* __restrict__ cf,
        const float* __restrict__ W3f, const float* __restrict__ vecf,
        float* __restrict__ out){
    __shared__ float w3s[4096];
    __shared__ float rows[4][64];
    for (int i = threadIdx.x; i < 4096; i += 256) w3s[i] = W3f[i];
    int w = threadIdx.x >> 6, f = threadIdx.x & 63;
    int n = blockIdx.x * 4 + w;
    float a = 0.f;
    int b = rp[n], e = rp[n + 1];
    for (int i = b; i < e; ++i){
        int s = csr[i];
        a += cf[i] * __bfloat162float(Yb[(size_t)s * 64 + f]);
    }
    rows[w][f] = a;
    __syncthreads();
    float acc = vecf[192 + f];                 // b3
    for (int k = 0; k < 64; k += 4){
        float4 rv = *(const float4*)&rows[w][k];
        acc += rv.x * w3s[k * 64 + f]       + rv.y * w3s[(k + 1) * 64 + f]
             + rv.z * w3s[(k + 2) * 64 + f] + rv.w * w3s[(k + 3) * 64 + f];
    }
    out[(size_t)n * 64 + f] = acc;
}

// ---------------- launch ----------------

extern "C" void kernel_launch(void* const* d_in, const int* in_sizes, int n_in,
                              void* d_out, int out_size, void* d_ws, size_t ws_size,
                              hipStream_t stream) {
    const void* x  = d_in[0];
    const int*  ei = (const int*)d_in[1];
    float* out = (float*)d_out;

    char* p = (char*)d_ws;
    auto alloc = [&](size_t bytes) -> void* {
        void* r = (void*)p;
        p += (bytes + 255) & ~(size_t)255;
        return r;
    };
    int*   flag     = (int*)  alloc(8);
    int*   deg      = (int*)  alloc((size_t)N_NODES * 4);
    int*   cursor   = (int*)  alloc((size_t)N_NODES * 4);
    int*   row_ptr  = (int*)  alloc((size_t)(N_NODES + 1) * 4);
    int*   blk      = (int*)  alloc(256 * 4);
    int*   csr      = (int*)  alloc((size_t)E_TOT * 4);
    float* coef     = (float*)alloc((size_t)E_TOT * 4);
    float* inv_sqrt = (float*)alloc((size_t)N_NODES * 4);
    float* a_src    = (float*)alloc((size_t)N_NODES * 2 * 4);
    float* a_dst    = (float*)alloc((size_t)N_NODES * 2 * 4);
    float* W1f      = (float*)alloc(16384 * 4);
    float* Wgf      = (float*)alloc(16384 * 4);
    float* W3f      = (float*)alloc(4096 * 4);
    float* vecf     = (float*)alloc(512 * 4);
    bf16*  xb       = (bf16*) alloc((size_t)N_NODES * 128 * 2);  // 12.8 MB
    bf16*  X2       = (bf16*) alloc((size_t)N_NODES * 128 * 2);  // 12.8 MB (interleaved)
    bf16*  Y        = (bf16*) alloc((size_t)N_NODES * 64 * 2);   //  6.4 MB
    // total ~41 MB

    const int NB_NODE = (N_NODES + 255) / 256;
    const int NB_EDGE = (E_TOT + 255) / 256;

    k_detect<<<1, 256, 0, stream>>>(ei, (const unsigned*)x, flag);
    k_convert<<<146, 256, 0, stream>>>(flag, d_in[2], d_in[4], d_in[8],
                                       d_in[3], d_in[7], d_in[9], d_in[5], d_in[6],
                                       W1f, Wgf, W3f, vecf);
    k_convx<<<(N_NODES * 128 + 255) / 256, 256, 0, stream>>>(x, flag, xb);

    k_zero2<<<NB_NODE, 256, 0, stream>>>(deg, cursor, N_NODES);
    k_count<<<NB_EDGE, 256, 0, stream>>>(ei, flag, deg);
    k_scanA<<<NB_NODE, 256, 0, stream>>>(deg, row_ptr, blk);
    k_scanB<<<1, 256, 0, stream>>>(blk, NB_NODE);
    k_scanC<<<NB_NODE, 256, 0, stream>>>(row_ptr, blk, deg, inv_sqrt);
    k_fill<<<NB_EDGE, 256, 0, stream>>>(ei, flag, row_ptr, inv_sqrt, cursor, csr, coef);

    k_mega1<<<N_NODES / 8, 256, 0, stream>>>((const ushort2*)xb, row_ptr, csr, coef,
                                             W1f, Wgf, vecf, X2, a_src, a_dst);
    k_gat<<<N_NODES / 4, 256, 0, stream>>>((const unsigned*)X2, row_ptr, csr,
                                           (const float2*)a_src, (const float2*)a_dst,
                                           vecf, Y);
    k_mega3<<<N_NODES / 4, 256, 0, stream>>>(Y, row_ptr, csr, coef, W3f, vecf, out);
}

// Round 9
// 548.178 us; speedup vs baseline: 1.9889x; 1.9889x over previous
//
#include <hip/hip_runtime.h>
#include <hip/hip_bf16.h>
#include <math.h>

#define N_NODES 50000
#define E0      800000
#define E_TOT   (E0 + N_NODES)

using bf16 = __hip_bfloat16;

static __device__ __forceinline__ float bfu2f_lo(unsigned u){ return __uint_as_float(u << 16); }
static __device__ __forceinline__ float bfu2f_hi(unsigned u){ return __uint_as_float(u & 0xffff0000u); }

// ---------------- init: zero deg/cursor + dtype autodetect ----------------
// flag[0]=1 -> edges int32 ; flag[1]=1 -> float tensors are fp32
__global__ void k_init(const int* __restrict__ ei, const unsigned* __restrict__ xu,
                       int* __restrict__ flag, int* __restrict__ deg,
                       int* __restrict__ cursor){
    int i = blockIdx.x * 256 + threadIdx.x;
    if (i < N_NODES){ deg[i] = 0; cursor[i] = 0; }
    if (blockIdx.x == gridDim.x - 1){
        __shared__ int e32, f32;
        if (threadIdx.x == 0){ e32 = 0; f32 = 0; }
        __syncthreads();
        if (ei[2 * threadIdx.x + 1] != 0) e32 = 1;        // int64 high words are 0
        if (threadIdx.x < 128){
            unsigned ex = (xu[threadIdx.x] >> 7) & 0xFF;  // bf16 exponent of low halfword
            if (ex < 100 || ex > 140) f32 = 1;            // fp32 mantissa bits look random
        }
        __syncthreads();
        if (threadIdx.x == 0){ flag[0] = e32; flag[1] = f32; }
    }
}

static __device__ __forceinline__ float ldany(const void* p, int i, int isf32){
    return isf32 ? ((const float*)p)[i] : __bfloat162float(((const bf16*)p)[i]);
}

// ---------------- convert weights->fp32 scratch AND x->bf16, one grid ----------------
// vecf layout: b1 @0(128), bg @128(64), b3 @192(64), att_s @256(128), att_d @384(128)
__global__ void k_convert(const int* __restrict__ flag, const void* __restrict__ xv,
                          const void* W1, const void* Wg, const void* W3,
                          const void* b1, const void* bg, const void* b3,
                          const void* as_, const void* ad_,
                          float* __restrict__ W1f, float* __restrict__ Wgf,
                          float* __restrict__ W3f, float* __restrict__ vecf,
                          bf16* __restrict__ xb){
    int isf = flag[1];
    int b = blockIdx.x, t = threadIdx.x;
    if (b >= 146){
        int i = (b - 146) * 256 + t;
        if (i < N_NODES * 128) xb[i] = __float2bfloat16(ldany(xv, i, isf));
        return;
    }
    if (b < 64){                 int i = b * 256 + t;         W1f[i] = ldany(W1, i, isf); }
    else if (b < 128){           int i = (b - 64) * 256 + t;  Wgf[i] = ldany(Wg, i, isf); }
    else if (b < 144){           int i = (b - 128) * 256 + t; W3f[i] = ldany(W3, i, isf); }
    else {
        int i = (b - 144) * 256 + t;     // 0..511
        float v;
        if      (i < 128) v = ldany(b1,  i,       isf);
        else if (i < 192) v = ldany(bg,  i - 128, isf);
        else if (i < 256) v = ldany(b3,  i - 192, isf);
        else if (i < 384) v = ldany(as_, i - 256, isf);
        else              v = ldany(ad_, i - 384, isf);
        vecf[i] = v;
    }
}

// ---------------- CSR build ----------------

static __device__ __forceinline__ int load_dst(const int* ei, int e, int is32){
    if (e >= E0) return e - E0;
    return is32 ? ei[E0 + e] : (int)((const long long*)ei)[E0 + e];
}
static __device__ __forceinline__ int load_src(const int* ei, int e, int is32){
    if (e >= E0) return e - E0;
    return is32 ? ei[e] : (int)((const long long*)ei)[e];
}

__global__ void k_count(const int* __restrict__ ei, const int* __restrict__ flag,
                        int* __restrict__ deg){
    int e = blockIdx.x * blockDim.x + threadIdx.x;
    if (e >= E_TOT) return;
    int is32 = flag[0];
    int dst = load_dst(ei, e, is32);
    int src = load_src(ei, e, is32);
    if ((unsigned)dst >= N_NODES || (unsigned)src >= N_NODES) return;
    atomicAdd(&deg[dst], 1);
}

__global__ void k_scanA(const int* __restrict__ deg, int* __restrict__ tmp, int* __restrict__ blk){
    __shared__ int s[256];
    int t = threadIdx.x;
    int i = blockIdx.x * 256 + t;
    int v = (i < N_NODES) ? deg[i] : 0;
    s[t] = v; __syncthreads();
    for (int off = 1; off < 256; off <<= 1){
        int x = (t >= off) ? s[t - off] : 0;
        __syncthreads();
        s[t] += x;
        __syncthreads();
    }
    if (t == 255) blk[blockIdx.x] = s[255];
    if (i < N_NODES) tmp[i] = s[t] - v;
}

__global__ void k_scanB(int* __restrict__ blk, int nb){
    __shared__ int s[256];
    int t = threadIdx.x;
    int v = (t < nb) ? blk[t] : 0;
    s[t] = v; __syncthreads();
    for (int off = 1; off < 256; off <<= 1){
        int x = (t >= off) ? s[t - off] : 0;
        __syncthreads();
        s[t] += x;
        __syncthreads();
    }
    if (t < nb) blk[t] = s[t] - v;
}

__global__ void k_scanC(int* __restrict__ row_ptr, const int* __restrict__ blk,
                        const int* __restrict__ deg, float* __restrict__ inv_sqrt){
    int i = blockIdx.x * blockDim.x + threadIdx.x;
    if (i < N_NODES){
        row_ptr[i] += blk[i >> 8];
        int d = deg[i];
        inv_sqrt[i] = (d > 0) ? rsqrtf((float)d) : 0.0f;
    }
    if (i == 0) row_ptr[N_NODES] = E_TOT;
}

// also writes coef[pos] = isq[dst]*isq[src]
__global__ void k_fill(const int* __restrict__ ei, const int* __restrict__ flag,
                       const int* __restrict__ row_ptr, const float* __restrict__ isq,
                       int* __restrict__ cursor, int* __restrict__ csr_src,
                       float* __restrict__ coef){
    int e = blockIdx.x * blockDim.x + threadIdx.x;
    if (e >= E_TOT) return;
    int is32 = flag[0];
    int dst = load_dst(ei, e, is32);
    int src = load_src(ei, e, is32);
    if ((unsigned)dst >= N_NODES || (unsigned)src >= N_NODES) return;
    int pos = row_ptr[dst] + atomicAdd(&cursor[dst], 1);
    csr_src[pos] = src;
    coef[pos] = isq[dst] * isq[src];
}

// ---------------- mega1: gather(xb) -> GEMM1+ReLU -> GEMM2 -> att logits ----------------
// R6-proven shape: 128 threads/block, 4 nodes/block, thread j owns feature column j.
// launch_bounds(128,4) caps VGPR at 128 (guards against regalloc cliffs, cf. R8).
// X2 stored interleaved: row n, bf16 slot (f*2 + head) so k_gat reads one u32/lane.
__global__ __launch_bounds__(128, 4) void k_mega1(
        const bf16* __restrict__ xb, const int* __restrict__ rp,
        const int* __restrict__ csr, const float* __restrict__ cf,
        const float* __restrict__ W1f, const float* __restrict__ Wgf,
        const float* __restrict__ vecf,
        bf16* __restrict__ X2, float* __restrict__ a_src, float* __restrict__ a_dst){
    __shared__ float as[4][128];
    __shared__ float hs[4][128];
    int n0 = blockIdx.x * 4;
    int j = threadIdx.x;

    // gather A_hat x rows (precomputed coef; csr/cf loads are wave-uniform)
    #pragma unroll
    for (int r = 0; r < 4; ++r){
        int n = n0 + r;
        float a = 0.f;
        int b = rp[n], e = rp[n + 1];
        for (int i = b; i < e; ++i){
            int s = csr[i];
            a += cf[i] * __bfloat162float(xb[(size_t)s * 128 + j]);
        }
        as[r][j] = a;
    }
    __syncthreads();

    // GEMM1 + b1 + ReLU (float4 LDS reads, k unroll 4)
    {
        float acc[4] = {0.f, 0.f, 0.f, 0.f};
        for (int k = 0; k < 128; k += 4){
            float w0 = W1f[k * 128 + j],       w1 = W1f[(k + 1) * 128 + j];
            float w2 = W1f[(k + 2) * 128 + j], w3 = W1f[(k + 3) * 128 + j];
            #pragma unroll
            for (int r = 0; r < 4; ++r){
                float4 av = *(const float4*)&as[r][k];
                acc[r] += av.x * w0 + av.y * w1 + av.z * w2 + av.w * w3;
            }
        }
        float bb = vecf[j];   // b1
        #pragma unroll
        for (int r = 0; r < 4; ++r) hs[r][j] = fmaxf(acc[r] + bb, 0.f);
    }
    __syncthreads();

    // GEMM2 (h2 = h @ Wg) + att logits + interleaved bf16 store
    float acc2[4] = {0.f, 0.f, 0.f, 0.f};
    for (int k = 0; k < 128; k += 4){
        float w0 = Wgf[k * 128 + j],       w1 = Wgf[(k + 1) * 128 + j];
        float w2 = Wgf[(k + 2) * 128 + j], w3 = Wgf[(k + 3) * 128 + j];
        #pragma unroll
        for (int r = 0; r < 4; ++r){
            float4 av = *(const float4*)&hs[r][k];
            acc2[r] += av.x * w0 + av.y * w1 + av.z * w2 + av.w * w3;
        }
    }
    float asv = vecf[256 + j], adv = vecf[384 + j];  // att_src, att_dst (head-major)
    int f = j & 63, h = j >> 6;                      // wave 0 = head 0, wave 1 = head 1
    #pragma unroll
    for (int r = 0; r < 4; ++r){
        int n = n0 + r;
        X2[(size_t)n * 128 + f * 2 + h] = __float2bfloat16(acc2[r]);
        float ps = acc2[r] * asv, pd = acc2[r] * adv;
        for (int off = 32; off; off >>= 1){
            ps += __shfl_down(ps, off, 64);
            pd += __shfl_down(pd, off, 64);
        }
        if (f == 0){
            a_src[n * 2 + h] = ps;
            a_dst[n * 2 + h] = pd;
        }
    }
}

// ---------------- GAT aggregate: softmax (no-max; logits bounded) + mean + bg + ELU ----
__global__ __launch_bounds__(256) void k_gat(
        const unsigned* __restrict__ X2u, const int* __restrict__ rp,
        const int* __restrict__ csr, const float2* __restrict__ a_src,
        const float2* __restrict__ a_dst, const float* __restrict__ vecf,
        bf16* __restrict__ Y){
    int n = blockIdx.x * 4 + (threadIdx.x >> 6);
    int f = threadIdx.x & 63;
    float2 ad = a_dst[n];
    float l0 = 0.f, l1 = 0.f, o0 = 0.f, o1 = 0.f;
    int b = rp[n], e = rp[n + 1];
    for (int i = b; i < e; ++i){
        int s = csr[i];
        float2 av = a_src[s];
        unsigned v = X2u[(size_t)s * 64 + f];          // both heads, one 4B load
        float e0 = av.x + ad.x, e1 = av.y + ad.y;
        e0 = (e0 > 0.f) ? e0 : 0.2f * e0;              // leaky_relu 0.2
        e1 = (e1 > 0.f) ? e1 : 0.2f * e1;
        float p0 = __expf(e0), p1 = __expf(e1);
        l0 += p0;  o0 += p0 * bfu2f_lo(v);
        l1 += p1;  o1 += p1 * bfu2f_hi(v);
    }
    float val = 0.5f * (o0 / l0 + o1 / l1) + vecf[128 + f];  // bg (self-loop => l>0)
    val = (val > 0.f) ? val : expm1f(val);                    // ELU alpha=1
    Y[(size_t)n * 64 + f] = __float2bfloat16(val);
}

// ---------------- mega3: gather(Y bf16) + W3 GEMM (W3 in LDS) -> out ----------------
__global__ __launch_bounds__(256) void k_mega3(
        const bf16* __restrict__ Yb, const int* __restrict__ rp,
        const int* __restrict__ csr, const float* __restrict__ cf,
        const float* __restrict__ W3f, const float* __restrict__ vecf,
        float* __restrict__ out){
    __shared__ float w3s[4096];
    __shared__ float rows[4][64];
    for (int i = threadIdx.x; i < 4096; i += 256) w3s[i] = W3f[i];
    int w = threadIdx.x >> 6, f = threadIdx.x & 63;
    int n = blockIdx.x * 4 + w;
    float a = 0.f;
    int b = rp[n], e = rp[n + 1];
    for (int i = b; i < e; ++i){
        int s = csr[i];
        a += cf[i] * __bfloat162float(Yb[(size_t)s * 64 + f]);
    }
    rows[w][f] = a;
    __syncthreads();
    float acc = vecf[192 + f];                 // b3
    for (int k = 0; k < 64; k += 4){
        float4 rv = *(const float4*)&rows[w][k];
        acc += rv.x * w3s[k * 64 + f]       + rv.y * w3s[(k + 1) * 64 + f]
             + rv.z * w3s[(k + 2) * 64 + f] + rv.w * w3s[(k + 3) * 64 + f];
    }
    out[(size_t)n * 64 + f] = acc;
}

// ---------------- launch ----------------

extern "C" void kernel_launch(void* const* d_in, const int* in_sizes, int n_in,
                              void* d_out, int out_size, void* d_ws, size_t ws_size,
                              hipStream_t stream) {
    const void* x  = d_in[0];
    const int*  ei = (const int*)d_in[1];
    float* out = (float*)d_out;

    char* p = (char*)d_ws;
    auto alloc = [&](size_t bytes) -> void* {
        void* r = (void*)p;
        p += (bytes + 255) & ~(size_t)255;
        return r;
    };
    int*   flag     = (int*)  alloc(8);
    int*   deg      = (int*)  alloc((size_t)N_NODES * 4);
    int*   cursor   = (int*)  alloc((size_t)N_NODES * 4);
    int*   row_ptr  = (int*)  alloc((size_t)(N_NODES + 1) * 4);
    int*   blk      = (int*)  alloc(256 * 4);
    int*   csr      = (int*)  alloc((size_t)E_TOT * 4);
    float* coef     = (float*)alloc((size_t)E_TOT * 4);
    float* inv_sqrt = (float*)alloc((size_t)N_NODES * 4);
    float* a_src    = (float*)alloc((size_t)N_NODES * 2 * 4);
    float* a_dst    = (float*)alloc((size_t)N_NODES * 2 * 4);
    float* W1f      = (float*)alloc(16384 * 4);
    float* Wgf      = (float*)alloc(16384 * 4);
    float* W3f      = (float*)alloc(4096 * 4);
    float* vecf     = (float*)alloc(512 * 4);
    bf16*  xb       = (bf16*) alloc((size_t)N_NODES * 128 * 2);  // 12.8 MB
    bf16*  X2       = (bf16*) alloc((size_t)N_NODES * 128 * 2);  // 12.8 MB (interleaved)
    bf16*  Y        = (bf16*) alloc((size_t)N_NODES * 64 * 2);   //  6.4 MB
    // total ~41 MB

    const int NB_NODE = (N_NODES + 255) / 256;          // 196
    const int NB_EDGE = (E_TOT + 255) / 256;
    const int NB_CONV = 146 + (N_NODES * 128 + 255) / 256;

    k_init<<<NB_NODE, 256, 0, stream>>>(ei, (const unsigned*)x, flag, deg, cursor);
    k_convert<<<NB_CONV, 256, 0, stream>>>(flag, x, d_in[2], d_in[4], d_in[8],
                                           d_in[3], d_in[7], d_in[9], d_in[5], d_in[6],
                                           W1f, Wgf, W3f, vecf, xb);

    k_count<<<NB_EDGE, 256, 0, stream>>>(ei, flag, deg);
    k_scanA<<<NB_NODE, 256, 0, stream>>>(deg, row_ptr, blk);
    k_scanB<<<1, 256, 0, stream>>>(blk, NB_NODE);
    k_scanC<<<NB_NODE, 256, 0, stream>>>(row_ptr, blk, deg, inv_sqrt);
    k_fill<<<NB_EDGE, 256, 0, stream>>>(ei, flag, row_ptr, inv_sqrt, cursor, csr, coef);

    k_mega1<<<N_NODES / 4, 128, 0, stream>>>(xb, row_ptr, csr, coef,
                                             W1f, Wgf, vecf, X2, a_src, a_dst);
    k_gat<<<N_NODES / 4, 256, 0, stream>>>((const unsigned*)X2, row_ptr, csr,
                                           (const float2*)a_src, (const float2*)a_dst,
                                           vecf, Y);
    k_mega3<<<N_NODES / 4, 256, 0, stream>>>(Y, row_ptr, csr, coef, W3f, vecf, out);
}

// Round 10
// 496.651 us; speedup vs baseline: 2.1953x; 1.1038x over previous
//
#include <hip/hip_runtime.h>
#include <hip/hip_bf16.h>
#include <math.h>

#define N_NODES 50000
#define E0      800000
#define E_TOT   (E0 + N_NODES)
#define SCAP    512            // staged edges per block (4 nodes, mean 68) — fallback if exceeded

using bf16 = __hip_bfloat16;

static __device__ __forceinline__ float bfu2f_lo(unsigned u){ return __uint_as_float(u << 16); }
static __device__ __forceinline__ float bfu2f_hi(unsigned u){ return __uint_as_float(u & 0xffff0000u); }

// per-wave dtype detects (one coalesced load + ballot; no cross-kernel flag dependency)
static __device__ __forceinline__ int detect_f32(const unsigned* xu){
    int lane = threadIdx.x & 63;
    unsigned ex = (xu[lane] >> 7) & 0xFF;          // bf16 exponent field of low halfword
    return (__ballot(ex < 100 || ex > 140) != 0ULL);  // fp32 mantissa bits look random
}
static __device__ __forceinline__ int detect_i32(const int* ei){
    int lane = threadIdx.x & 63;
    return (__ballot(ei[2 * lane + 1] != 0) != 0ULL);  // int64 high words are all 0
}

static __device__ __forceinline__ float ldany(const void* p, int i, int isf32){
    return isf32 ? ((const float*)p)[i] : __bfloat162float(((const bf16*)p)[i]);
}

// ---------------- convert weights->fp32, x->bf16, zero deg/cursor — one grid ----------------
// vecf layout: b1 @0(128), bg @128(64), b3 @192(64), att_s @256(128), att_d @384(128)
// blocks [0,146): weights/vecs; [146, 146+NXB): x->bf16; rest: zero deg/cursor
__global__ void k_convert(const void* __restrict__ xv,
                          const void* W1, const void* Wg, const void* W3,
                          const void* b1, const void* bg, const void* b3,
                          const void* as_, const void* ad_,
                          float* __restrict__ W1f, float* __restrict__ Wgf,
                          float* __restrict__ W3f, float* __restrict__ vecf,
                          bf16* __restrict__ xb, int* __restrict__ deg,
                          int* __restrict__ cursor){
    const int NXB = (N_NODES * 128 + 255) / 256;
    int b = blockIdx.x, t = threadIdx.x;
    if (b >= 146 + NXB){                      // zeroing tail
        int i = (b - 146 - NXB) * 256 + t;
        if (i < N_NODES){ deg[i] = 0; cursor[i] = 0; }
        return;
    }
    int isf = detect_f32((const unsigned*)xv);
    if (b >= 146){
        int i = (b - 146) * 256 + t;
        if (i < N_NODES * 128) xb[i] = __float2bfloat16(ldany(xv, i, isf));
        return;
    }
    if (b < 64){                 int i = b * 256 + t;         W1f[i] = ldany(W1, i, isf); }
    else if (b < 128){           int i = (b - 64) * 256 + t;  Wgf[i] = ldany(Wg, i, isf); }
    else if (b < 144){           int i = (b - 128) * 256 + t; W3f[i] = ldany(W3, i, isf); }
    else {
        int i = (b - 144) * 256 + t;     // 0..511
        float v;
        if      (i < 128) v = ldany(b1,  i,       isf);
        else if (i < 192) v = ldany(bg,  i - 128, isf);
        else if (i < 256) v = ldany(b3,  i - 192, isf);
        else if (i < 384) v = ldany(as_, i - 256, isf);
        else              v = ldany(ad_, i - 384, isf);
        vecf[i] = v;
    }
}

// ---------------- CSR build ----------------

static __device__ __forceinline__ int load_dst(const int* ei, int e, int is32){
    if (e >= E0) return e - E0;
    return is32 ? ei[E0 + e] : (int)((const long long*)ei)[E0 + e];
}
static __device__ __forceinline__ int load_src(const int* ei, int e, int is32){
    if (e >= E0) return e - E0;
    return is32 ? ei[e] : (int)((const long long*)ei)[e];
}

__global__ void k_count(const int* __restrict__ ei, int* __restrict__ deg){
    int is32 = detect_i32(ei);
    int e = blockIdx.x * blockDim.x + threadIdx.x;
    if (e >= E_TOT) return;
    int dst = load_dst(ei, e, is32);
    int src = load_src(ei, e, is32);
    if ((unsigned)dst >= N_NODES || (unsigned)src >= N_NODES) return;
    atomicAdd(&deg[dst], 1);
}

__global__ void k_scanA(const int* __restrict__ deg, int* __restrict__ tmp, int* __restrict__ blk){
    __shared__ int s[256];
    int t = threadIdx.x;
    int i = blockIdx.x * 256 + t;
    int v = (i < N_NODES) ? deg[i] : 0;
    s[t] = v; __syncthreads();
    for (int off = 1; off < 256; off <<= 1){
        int x = (t >= off) ? s[t - off] : 0;
        __syncthreads();
        s[t] += x;
        __syncthreads();
    }
    if (t == 255) blk[blockIdx.x] = s[255];
    if (i < N_NODES) tmp[i] = s[t] - v;
}

__global__ void k_scanB(int* __restrict__ blk, int nb){
    __shared__ int s[256];
    int t = threadIdx.x;
    int v = (t < nb) ? blk[t] : 0;
    s[t] = v; __syncthreads();
    for (int off = 1; off < 256; off <<= 1){
        int x = (t >= off) ? s[t - off] : 0;
        __syncthreads();
        s[t] += x;
        __syncthreads();
    }
    if (t < nb) blk[t] = s[t] - v;
}

__global__ void k_scanC(int* __restrict__ row_ptr, const int* __restrict__ blk,
                        const int* __restrict__ deg, float* __restrict__ inv_sqrt){
    int i = blockIdx.x * blockDim.x + threadIdx.x;
    if (i < N_NODES){
        row_ptr[i] += blk[i >> 8];
        int d = deg[i];
        inv_sqrt[i] = (d > 0) ? rsqrtf((float)d) : 0.0f;
    }
    if (i == 0) row_ptr[N_NODES] = E_TOT;
}

// also writes coef[pos] = isq[dst]*isq[src]
__global__ void k_fill(const int* __restrict__ ei, const int* __restrict__ row_ptr,
                       const float* __restrict__ isq, int* __restrict__ cursor,
                       int* __restrict__ csr_src, float* __restrict__ coef){
    int is32 = detect_i32(ei);
    int e = blockIdx.x * blockDim.x + threadIdx.x;
    if (e >= E_TOT) return;
    int dst = load_dst(ei, e, is32);
    int src = load_src(ei, e, is32);
    if ((unsigned)dst >= N_NODES || (unsigned)src >= N_NODES) return;
    int pos = row_ptr[dst] + atomicAdd(&cursor[dst], 1);
    csr_src[pos] = src;
    coef[pos] = isq[dst] * isq[src];
}

// ---------------- mega1: gather(xb) -> GEMM1+ReLU -> GEMM2 -> att logits ----------------
// 128 threads/block, 4 nodes/block, thread j owns feature column j (R6-proven shape).
// Edge lists staged to LDS first: kills the per-edge dependent csr->row latency chain.
// X2 stored interleaved: row n, bf16 slot (f*2 + head) so k_gat reads one u32/lane.
__global__ __launch_bounds__(128, 4) void k_mega1(
        const bf16* __restrict__ xb, const int* __restrict__ rp,
        const int* __restrict__ csr, const float* __restrict__ cf,
        const float* __restrict__ W1f, const float* __restrict__ Wgf,
        const float* __restrict__ vecf,
        bf16* __restrict__ X2, float* __restrict__ a_src, float* __restrict__ a_dst){
    __shared__ float as[4][128];
    __shared__ float hs[4][128];
    __shared__ int   scsr[SCAP];
    __shared__ float scf[SCAP];
    int n0 = blockIdx.x * 4;
    int j = threadIdx.x;

    int b0 = rp[n0];
    int tot  = rp[n0 + 4] - b0;
    int stot = min(tot, SCAP);
    for (int i = j; i < stot; i += 128){       // coalesced stage
        scsr[i] = csr[b0 + i];
        scf[i]  = cf[b0 + i];
    }
    __syncthreads();

    #pragma unroll
    for (int r = 0; r < 4; ++r){
        int n = n0 + r;
        float a = 0.f;
        int b = rp[n] - b0, e = rp[n + 1] - b0;
        int elim = min(e, stot);
        for (int i = b; i < elim; ++i)          // independent row loads, LDS indices
            a += scf[i] * __bfloat162float(xb[(size_t)scsr[i] * 128 + j]);
        for (int i = max(b, stot); i < e; ++i)  // fallback (pathological degrees only)
            a += cf[b0 + i] * __bfloat162float(xb[(size_t)csr[b0 + i] * 128 + j]);
        as[r][j] = a;
    }
    __syncthreads();

    // GEMM1 + b1 + ReLU (float4 LDS broadcasts, k unroll 4)
    {
        float acc[4] = {0.f, 0.f, 0.f, 0.f};
        for (int k = 0; k < 128; k += 4){
            float w0 = W1f[k * 128 + j],       w1 = W1f[(k + 1) * 128 + j];
            float w2 = W1f[(k + 2) * 128 + j], w3 = W1f[(k + 3) * 128 + j];
            #pragma unroll
            for (int r = 0; r < 4; ++r){
                float4 av = *(const float4*)&as[r][k];
                acc[r] += av.x * w0 + av.y * w1 + av.z * w2 + av.w * w3;
            }
        }
        float bb = vecf[j];   // b1
        #pragma unroll
        for (int r = 0; r < 4; ++r) hs[r][j] = fmaxf(acc[r] + bb, 0.f);
    }
    __syncthreads();

    // GEMM2 (h2 = h @ Wg) + att logits + interleaved bf16 store
    float acc2[4] = {0.f, 0.f, 0.f, 0.f};
    for (int k = 0; k < 128; k += 4){
        float w0 = Wgf[k * 128 + j],       w1 = Wgf[(k + 1) * 128 + j];
        float w2 = Wgf[(k + 2) * 128 + j], w3 = Wgf[(k + 3) * 128 + j];
        #pragma unroll
        for (int r = 0; r < 4; ++r){
            float4 av = *(const float4*)&hs[r][k];
            acc2[r] += av.x * w0 + av.y * w1 + av.z * w2 + av.w * w3;
        }
    }
    float asv = vecf[256 + j], adv = vecf[384 + j];  // att_src, att_dst (head-major)
    int f = j & 63, h = j >> 6;                      // wave 0 = head 0, wave 1 = head 1
    #pragma unroll
    for (int r = 0; r < 4; ++r){
        int n = n0 + r;
        X2[(size_t)n * 128 + f * 2 + h] = __float2bfloat16(acc2[r]);
        float ps = acc2[r] * asv, pd = acc2[r] * adv;
        for (int off = 32; off; off >>= 1){
            ps += __shfl_down(ps, off, 64);
            pd += __shfl_down(pd, off, 64);
        }
        if (f == 0){
            a_src[n * 2 + h] = ps;
            a_dst[n * 2 + h] = pd;
        }
    }
}

// ---------------- GAT aggregate: softmax (no-max; logits bounded) + mean + bg + ELU ----
__global__ __launch_bounds__(256) void k_gat(
        const unsigned* __restrict__ X2u, const int* __restrict__ rp,
        const int* __restrict__ csr, const float2* __restrict__ a_src,
        const float2* __restrict__ a_dst, const float* __restrict__ vecf,
        bf16* __restrict__ Y){
    __shared__ int scsr[SCAP];
    int n0 = blockIdx.x * 4;
    int b0 = rp[n0];
    int tot  = rp[n0 + 4] - b0;
    int stot = min(tot, SCAP);
    for (int i = threadIdx.x; i < stot; i += 256) scsr[i] = csr[b0 + i];
    __syncthreads();

    int n = n0 + (threadIdx.x >> 6);
    int f = threadIdx.x & 63;
    float2 ad = a_dst[n];
    float l0 = 0.f, l1 = 0.f, o0 = 0.f, o1 = 0.f;
    int b = rp[n] - b0, e = rp[n + 1] - b0;
    int elim = min(e, stot);
    for (int i = b; i < elim; ++i){
        int s = scsr[i];
        float2 av = a_src[s];
        unsigned v = X2u[(size_t)s * 64 + f];          // both heads, one 4B load
        float e0 = av.x + ad.x, e1 = av.y + ad.y;
        e0 = (e0 > 0.f) ? e0 : 0.2f * e0;              // leaky_relu 0.2
        e1 = (e1 > 0.f) ? e1 : 0.2f * e1;
        float p0 = __expf(e0), p1 = __expf(e1);
        l0 += p0;  o0 += p0 * bfu2f_lo(v);
        l1 += p1;  o1 += p1 * bfu2f_hi(v);
    }
    for (int i = max(b, stot); i < e; ++i){            // fallback
        int s = csr[b0 + i];
        float2 av = a_src[s];
        unsigned v = X2u[(size_t)s * 64 + f];
        float e0 = av.x + ad.x, e1 = av.y + ad.y;
        e0 = (e0 > 0.f) ? e0 : 0.2f * e0;
        e1 = (e1 > 0.f) ? e1 : 0.2f * e1;
        float p0 = __expf(e0), p1 = __expf(e1);
        l0 += p0;  o0 += p0 * bfu2f_lo(v);
        l1 += p1;  o1 += p1 * bfu2f_hi(v);
    }
    float val = 0.5f * (o0 / l0 + o1 / l1) + vecf[128 + f];  // bg (self-loop => l>0)
    val = (val > 0.f) ? val : expm1f(val);                    // ELU alpha=1
    Y[(size_t)n * 64 + f] = __float2bfloat16(val);
}

// ---------------- mega3: gather(Y bf16) + W3 GEMM (W3 in LDS) -> out ----------------
__global__ __launch_bounds__(256) void k_mega3(
        const bf16* __restrict__ Yb, const int* __restrict__ rp,
        const int* __restrict__ csr, const float* __restrict__ cf,
        const float* __restrict__ W3f, const float* __restrict__ vecf,
        float* __restrict__ out){
    __shared__ float w3s[4096];
    __shared__ float rows[4][64];
    __shared__ int   scsr[SCAP];
    __shared__ float scf[SCAP];
    int n0 = blockIdx.x * 4;
    int b0 = rp[n0];
    int tot  = rp[n0 + 4] - b0;
    int stot = min(tot, SCAP);
    for (int i = threadIdx.x; i < stot; i += 256){
        scsr[i] = csr[b0 + i];
        scf[i]  = cf[b0 + i];
    }
    for (int i = threadIdx.x; i < 4096; i += 256) w3s[i] = W3f[i];
    __syncthreads();

    int w = threadIdx.x >> 6, f = threadIdx.x & 63;
    int n = n0 + w;
    float a = 0.f;
    int b = rp[n] - b0, e = rp[n + 1] - b0;
    int elim = min(e, stot);
    for (int i = b; i < elim; ++i)
        a += scf[i] * __bfloat162float(Yb[(size_t)scsr[i] * 64 + f]);
    for (int i = max(b, stot); i < e; ++i)             // fallback
        a += cf[b0 + i] * __bfloat162float(Yb[(size_t)csr[b0 + i] * 64 + f]);
    rows[w][f] = a;
    __syncthreads();
    float acc = vecf[192 + f];                 // b3
    for (int k = 0; k < 64; k += 4){
        float4 rv = *(const float4*)&rows[w][k];
        acc += rv.x * w3s[k * 64 + f]       + rv.y * w3s[(k + 1) * 64 + f]
             + rv.z * w3s[(k + 2) * 64 + f] + rv.w * w3s[(k + 3) * 64 + f];
    }
    out[(size_t)n * 64 + f] = acc;
}

// ---------------- launch ----------------

extern "C" void kernel_launch(void* const* d_in, const int* in_sizes, int n_in,
                              void* d_out, int out_size, void* d_ws, size_t ws_size,
                              hipStream_t stream) {
    const void* x  = d_in[0];
    const int*  ei = (const int*)d_in[1];
    float* out = (float*)d_out;

    char* p = (char*)d_ws;
    auto alloc = [&](size_t bytes) -> void* {
        void* r = (void*)p;
        p += (bytes + 255) & ~(size_t)255;
        return r;
    };
    int*   deg      = (int*)  alloc((size_t)N_NODES * 4);
    int*   cursor   = (int*)  alloc((size_t)N_NODES * 4);
    int*   row_ptr  = (int*)  alloc((size_t)(N_NODES + 1) * 4);
    int*   blk      = (int*)  alloc(256 * 4);
    int*   csr      = (int*)  alloc((size_t)E_TOT * 4);
    float* coef     = (float*)alloc((size_t)E_TOT * 4);
    float* inv_sqrt = (float*)alloc((size_t)N_NODES * 4);
    float* a_src    = (float*)alloc((size_t)N_NODES * 2 * 4);
    float* a_dst    = (float*)alloc((size_t)N_NODES * 2 * 4);
    float* W1f      = (float*)alloc(16384 * 4);
    float* Wgf      = (float*)alloc(16384 * 4);
    float* W3f      = (float*)alloc(4096 * 4);
    float* vecf     = (float*)alloc(512 * 4);
    bf16*  xb       = (bf16*) alloc((size_t)N_NODES * 128 * 2);  // 12.8 MB
    bf16*  X2       = (bf16*) alloc((size_t)N_NODES * 128 * 2);  // 12.8 MB (interleaved)
    bf16*  Y        = (bf16*) alloc((size_t)N_NODES * 64 * 2);   //  6.4 MB
    // total ~41 MB

    const int NB_NODE = (N_NODES + 255) / 256;              // 196
    const int NB_EDGE = (E_TOT + 255) / 256;
    const int NXB     = (N_NODES * 128 + 255) / 256;
    const int NB_CONV = 146 + NXB + NB_NODE;

    k_convert<<<NB_CONV, 256, 0, stream>>>(x, d_in[2], d_in[4], d_in[8],
                                           d_in[3], d_in[7], d_in[9], d_in[5], d_in[6],
                                           W1f, Wgf, W3f, vecf, xb, deg, cursor);
    k_count<<<NB_EDGE, 256, 0, stream>>>(ei, deg);
    k_scanA<<<NB_NODE, 256, 0, stream>>>(deg, row_ptr, blk);
    k_scanB<<<1, 256, 0, stream>>>(blk, NB_NODE);
    k_scanC<<<NB_NODE, 256, 0, stream>>>(row_ptr, blk, deg, inv_sqrt);
    k_fill<<<NB_EDGE, 256, 0, stream>>>(ei, row_ptr, inv_sqrt, cursor, csr, coef);

    k_mega1<<<N_NODES / 4, 128, 0, stream>>>(xb, row_ptr, csr, coef,
                                             W1f, Wgf, vecf, X2, a_src, a_dst);
    k_gat<<<N_NODES / 4, 256, 0, stream>>>((const unsigned*)X2, row_ptr, csr,
                                           (const float2*)a_src, (const float2*)a_dst,
                                           vecf, Y);
    k_mega3<<<N_NODES / 4, 256, 0, stream>>>(Y, row_ptr, csr, coef, W3f, vecf, out);
}

// Round 11
// 482.399 us; speedup vs baseline: 2.2601x; 1.0295x over previous
//
#include <hip/hip_runtime.h>
#include <hip/hip_bf16.h>
#include <math.h>

#define N_NODES 50000
#define E0      800000
#define E_TOT   (E0 + N_NODES)
#define SCAP    512

using bf16 = __hip_bfloat16;
typedef __attribute__((ext_vector_type(8))) short bfrag;   // 8 bf16 (4 VGPRs)
typedef __attribute__((ext_vector_type(4))) float ffrag;   // 4 fp32 acc

static __device__ __forceinline__ float bfu2f_lo(unsigned u){ return __uint_as_float(u << 16); }
static __device__ __forceinline__ float bfu2f_hi(unsigned u){ return __uint_as_float(u & 0xffff0000u); }

// per-wave dtype detects (one coalesced load + ballot)
static __device__ __forceinline__ int detect_f32(const unsigned* xu){
    int lane = threadIdx.x & 63;
    unsigned ex = (xu[lane] >> 7) & 0xFF;
    return (__ballot(ex < 100 || ex > 140) != 0ULL);
}
static __device__ __forceinline__ int detect_i32(const int* ei){
    int lane = threadIdx.x & 63;
    return (__ballot(ei[2 * lane + 1] != 0) != 0ULL);
}

static __device__ __forceinline__ float ldany(const void* p, int i, int isf32){
    return isf32 ? ((const float*)p)[i] : __bfloat162float(((const bf16*)p)[i]);
}

// ---------------- convert: W3->fp32, vecs->fp32, W1/Wg -> packed bf16 MFMA frags,
// x->bf16, zero deg/cursor — one grid.
// vecf: b1 @0(128), bg @128(64), b3 @192(64), att_s @256(128), att_d @384(128)
// packed W layout: elem ((ct*4+kc)*64+L)*8+j  <-  W[(kc*32+(L>>4)*8+j)*128 + (ct*16+(L&15))]
__global__ void k_convert(const void* __restrict__ xv,
                          const void* W1, const void* Wg, const void* W3,
                          const void* b1, const void* bg, const void* b3,
                          const void* as_, const void* ad_,
                          bf16* __restrict__ W1p, bf16* __restrict__ Wgp,
                          float* __restrict__ W3f, float* __restrict__ vecf,
                          bf16* __restrict__ xb, int* __restrict__ deg,
                          int* __restrict__ cursor){
    const int NXB = (N_NODES * 128 + 255) / 256;
    int b = blockIdx.x, t = threadIdx.x;
    if (b >= 146 + NXB){
        int i = (b - 146 - NXB) * 256 + t;
        if (i < N_NODES){ deg[i] = 0; cursor[i] = 0; }
        return;
    }
    int isf = detect_f32((const unsigned*)xv);
    if (b >= 146){
        int i = (b - 146) * 256 + t;
        if (i < N_NODES * 128) xb[i] = __float2bfloat16(ldany(xv, i, isf));
        return;
    }
    if (b < 16){            int i = b * 256 + t; W3f[i] = ldany(W3, i, isf); }
    else if (b < 18){
        int i = (b - 16) * 256 + t;     // 0..511
        float v;
        if      (i < 128) v = ldany(b1,  i,       isf);
        else if (i < 192) v = ldany(bg,  i - 128, isf);
        else if (i < 256) v = ldany(b3,  i - 192, isf);
        else if (i < 384) v = ldany(as_, i - 256, isf);
        else              v = ldany(ad_, i - 384, isf);
        vecf[i] = v;
    } else {
        int d = (b - 18) * 256 + t;          // 0..16383 per W, two Ws
        const void* Wsrc = (d < 16384) ? W1 : Wg;
        bf16* Wdst = (d < 16384) ? W1p : Wgp;
        int dd = d & 16383;
        int j  = dd & 7;
        int L  = (dd >> 3) & 63;
        int kc = (dd >> 9) & 3;
        int ct = dd >> 11;
        int k = kc * 32 + ((L >> 4) << 3) + j;
        int n = ct * 16 + (L & 15);
        Wdst[dd] = __float2bfloat16(ldany(Wsrc, k * 128 + n, isf));
    }
}

// ---------------- CSR build ----------------

static __device__ __forceinline__ int load_dst(const int* ei, int e, int is32){
    if (e >= E0) return e - E0;
    return is32 ? ei[E0 + e] : (int)((const long long*)ei)[E0 + e];
}
static __device__ __forceinline__ int load_src(const int* ei, int e, int is32){
    if (e >= E0) return e - E0;
    return is32 ? ei[e] : (int)((const long long*)ei)[e];
}

__global__ void k_count(const int* __restrict__ ei, int* __restrict__ deg){
    int is32 = detect_i32(ei);
    int e = blockIdx.x * blockDim.x + threadIdx.x;
    if (e >= E_TOT) return;
    int dst = load_dst(ei, e, is32);
    int src = load_src(ei, e, is32);
    if ((unsigned)dst >= N_NODES || (unsigned)src >= N_NODES) return;
    atomicAdd(&deg[dst], 1);
}

__global__ void k_scanA(const int* __restrict__ deg, int* __restrict__ tmp, int* __restrict__ blk){
    __shared__ int s[256];
    int t = threadIdx.x;
    int i = blockIdx.x * 256 + t;
    int v = (i < N_NODES) ? deg[i] : 0;
    s[t] = v; __syncthreads();
    for (int off = 1; off < 256; off <<= 1){
        int x = (t >= off) ? s[t - off] : 0;
        __syncthreads();
        s[t] += x;
        __syncthreads();
    }
    if (t == 255) blk[blockIdx.x] = s[255];
    if (i < N_NODES) tmp[i] = s[t] - v;
}

__global__ void k_scanB(int* __restrict__ blk, int nb){
    __shared__ int s[256];
    int t = threadIdx.x;
    int v = (t < nb) ? blk[t] : 0;
    s[t] = v; __syncthreads();
    for (int off = 1; off < 256; off <<= 1){
        int x = (t >= off) ? s[t - off] : 0;
        __syncthreads();
        s[t] += x;
        __syncthreads();
    }
    if (t < nb) blk[t] = s[t] - v;
}

__global__ void k_scanC(int* __restrict__ row_ptr, const int* __restrict__ blk,
                        const int* __restrict__ deg, float* __restrict__ inv_sqrt){
    int i = blockIdx.x * blockDim.x + threadIdx.x;
    if (i < N_NODES){
        row_ptr[i] += blk[i >> 8];
        int d = deg[i];
        inv_sqrt[i] = (d > 0) ? rsqrtf((float)d) : 0.0f;
    }
    if (i == 0) row_ptr[N_NODES] = E_TOT;
}

__global__ void k_fill(const int* __restrict__ ei, const int* __restrict__ row_ptr,
                       const float* __restrict__ isq, int* __restrict__ cursor,
                       int* __restrict__ csr_src, float* __restrict__ coef){
    int is32 = detect_i32(ei);
    int e = blockIdx.x * blockDim.x + threadIdx.x;
    if (e >= E_TOT) return;
    int dst = load_dst(ei, e, is32);
    int src = load_src(ei, e, is32);
    if ((unsigned)dst >= N_NODES || (unsigned)src >= N_NODES) return;
    int pos = row_ptr[dst] + atomicAdd(&cursor[dst], 1);
    csr_src[pos] = src;
    coef[pos] = isq[dst] * isq[src];
}

// ---------------- gather: Xa = A_hat x  (R10-proven shape, bf16 out) ----------------
__global__ __launch_bounds__(128, 4) void k_gather(
        const bf16* __restrict__ xb, const int* __restrict__ rp,
        const int* __restrict__ csr, const float* __restrict__ cf,
        bf16* __restrict__ Xa){
    __shared__ int   scsr[SCAP];
    __shared__ float scf[SCAP];
    int n0 = blockIdx.x * 4;
    int j = threadIdx.x;

    int b0 = rp[n0];
    int tot  = rp[n0 + 4] - b0;
    int stot = min(tot, SCAP);
    for (int i = j; i < stot; i += 128){
        scsr[i] = csr[b0 + i];
        scf[i]  = cf[b0 + i];
    }
    __syncthreads();

    #pragma unroll
    for (int r = 0; r < 4; ++r){
        int n = n0 + r;
        float a = 0.f;
        int b = rp[n] - b0, e = rp[n + 1] - b0;
        int elim = min(e, stot);
        for (int i = b; i < elim; ++i)
            a += scf[i] * __bfloat162float(xb[(size_t)scsr[i] * 128 + j]);
        for (int i = max(b, stot); i < e; ++i)
            a += cf[b0 + i] * __bfloat162float(xb[(size_t)csr[b0 + i] * 128 + j]);
        Xa[(size_t)n * 128 + j] = __float2bfloat16(a);
    }
}

// ---------------- MFMA GEMM: O = A(N,128)bf16 @ Wp(128x128 packed) [+b1,relu | interleave]
// 512 threads = 8 waves; block = one 16-row tile; wave w = col-tile w.
// Layouts (HW-verified, learn_hip m89/m91/m120):
//   A frag : lane holds A[m=lane&15][k=(lane>>4)*8+j], j=0..7 -> 16B contiguous row load
//   B frag : lane holds W[k=(lane>>4)*8+j][n=lane&15]         -> pre-packed contiguous
//   C/D    : col=lane&15, row=(lane>>4)*4+reg
// In-place safe: __syncthreads() between all A reads and any store; blocks own disjoint rows.
template<int EPI>
__global__ __launch_bounds__(512) void k_gemm_mfma(
        const bf16* __restrict__ A, const bf16* __restrict__ Wp,
        const float* __restrict__ vecf, bf16* __restrict__ O){
    int wid  = threadIdx.x >> 6;          // col tile 0..7
    int lane = threadIdx.x & 63;
    int n0 = blockIdx.x * 16;
    int m = lane & 15, q = lane >> 4;

    const bfrag* Ap = (const bfrag*)(A + (size_t)(n0 + m) * 128);   // +i covers k [i*8, i*8+8)
    const bfrag* Bp = (const bfrag*)Wp + (size_t)wid * 256 + lane;  // [ct][kc][lane]

    ffrag c = {0.f, 0.f, 0.f, 0.f};
    #pragma unroll
    for (int kc = 0; kc < 4; ++kc){
        bfrag af = Ap[kc * 4 + q];
        bfrag bf = Bp[kc * 64];
        c = __builtin_amdgcn_mfma_f32_16x16x32_bf16(af, bf, c, 0, 0, 0);
    }
    __syncthreads();                      // all A reads done -> in-place stores safe

    int col = wid * 16 + m;
    if (EPI == 0){
        float bb = vecf[col];             // b1
        #pragma unroll
        for (int r = 0; r < 4; ++r){
            int row = n0 + q * 4 + r;
            O[(size_t)row * 128 + col] = __float2bfloat16(fmaxf(c[r] + bb, 0.f));
        }
    } else {                              // interleaved X2: slot (f*2 + head)
        int f = col & 63, h = col >> 6;
        #pragma unroll
        for (int r = 0; r < 4; ++r){
            int row = n0 + q * 4 + r;
            O[(size_t)row * 128 + f * 2 + h] = __float2bfloat16(c[r]);
        }
    }
}

// ---------------- att logits: per-node wave reduce over interleaved X2 ----------------
__global__ __launch_bounds__(256) void k_att(
        const unsigned* __restrict__ X2u, const float* __restrict__ vecf,
        float2* __restrict__ a_src, float2* __restrict__ a_dst){
    int n = blockIdx.x * 4 + (threadIdx.x >> 6);
    int l = threadIdx.x & 63;
    unsigned v = X2u[(size_t)n * 64 + l];
    float x0 = bfu2f_lo(v), x1 = bfu2f_hi(v);
    float s0 = x0 * vecf[256 + l], s1 = x1 * vecf[320 + l];
    float d0 = x0 * vecf[384 + l], d1 = x1 * vecf[448 + l];
    for (int off = 32; off; off >>= 1){
        s0 += __shfl_down(s0, off, 64);  s1 += __shfl_down(s1, off, 64);
        d0 += __shfl_down(d0, off, 64);  d1 += __shfl_down(d1, off, 64);
    }
    if (l == 0){
        a_src[n] = make_float2(s0, s1);
        a_dst[n] = make_float2(d0, d1);
    }
}

// ---------------- GAT aggregate: softmax (no-max; logits bounded) + mean + bg + ELU ----
__global__ __launch_bounds__(256) void k_gat(
        const unsigned* __restrict__ X2u, const int* __restrict__ rp,
        const int* __restrict__ csr, const float2* __restrict__ a_src,
        const float2* __restrict__ a_dst, const float* __restrict__ vecf,
        bf16* __restrict__ Y){
    __shared__ int scsr[SCAP];
    int n0 = blockIdx.x * 4;
    int b0 = rp[n0];
    int tot  = rp[n0 + 4] - b0;
    int stot = min(tot, SCAP);
    for (int i = threadIdx.x; i < stot; i += 256) scsr[i] = csr[b0 + i];
    __syncthreads();

    int n = n0 + (threadIdx.x >> 6);
    int f = threadIdx.x & 63;
    float2 ad = a_dst[n];
    float l0 = 0.f, l1 = 0.f, o0 = 0.f, o1 = 0.f;
    int b = rp[n] - b0, e = rp[n + 1] - b0;
    int elim = min(e, stot);
    for (int i = b; i < elim; ++i){
        int s = scsr[i];
        float2 av = a_src[s];
        unsigned v = X2u[(size_t)s * 64 + f];
        float e0 = av.x + ad.x, e1 = av.y + ad.y;
        e0 = (e0 > 0.f) ? e0 : 0.2f * e0;
        e1 = (e1 > 0.f) ? e1 : 0.2f * e1;
        float p0 = __expf(e0), p1 = __expf(e1);
        l0 += p0;  o0 += p0 * bfu2f_lo(v);
        l1 += p1;  o1 += p1 * bfu2f_hi(v);
    }
    for (int i = max(b, stot); i < e; ++i){
        int s = csr[b0 + i];
        float2 av = a_src[s];
        unsigned v = X2u[(size_t)s * 64 + f];
        float e0 = av.x + ad.x, e1 = av.y + ad.y;
        e0 = (e0 > 0.f) ? e0 : 0.2f * e0;
        e1 = (e1 > 0.f) ? e1 : 0.2f * e1;
        float p0 = __expf(e0), p1 = __expf(e1);
        l0 += p0;  o0 += p0 * bfu2f_lo(v);
        l1 += p1;  o1 += p1 * bfu2f_hi(v);
    }
    float val = 0.5f * (o0 / l0 + o1 / l1) + vecf[128 + f];
    val = (val > 0.f) ? val : expm1f(val);
    Y[(size_t)n * 64 + f] = __float2bfloat16(val);
}

// ---------------- mega3: gather(Y bf16) + W3 GEMM (W3 in LDS) -> out ----------------
__global__ __launch_bounds__(256) void k_mega3(
        const bf16* __restrict__ Yb, const int* __restrict__ rp,
        const int* __restrict__ csr, const float* __restrict__ cf,
        const float* __restrict__ W3f, const float* __restrict__ vecf,
        float* __restrict__ out){
    __shared__ float w3s[4096];
    __shared__ float rows[4][64];
    __shared__ int   scsr[SCAP];
    __shared__ float scf[SCAP];
    int n0 = blockIdx.x * 4;
    int b0 = rp[n0];
    int tot  = rp[n0 + 4] - b0;
    int stot = min(tot, SCAP);
    for (int i = threadIdx.x; i < stot; i += 256){
        scsr[i] = csr[b0 + i];
        scf[i]  = cf[b0 + i];
    }
    for (int i = threadIdx.x; i < 4096; i += 256) w3s[i] = W3f[i];
    __syncthreads();

    int w = threadIdx.x >> 6, f = threadIdx.x & 63;
    int n = n0 + w;
    float a = 0.f;
    int b = rp[n] - b0, e = rp[n + 1] - b0;
    int elim = min(e, stot);
    for (int i = b; i < elim; ++i)
        a += scf[i] * __bfloat162float(Yb[(size_t)scsr[i] * 64 + f]);
    for (int i = max(b, stot); i < e; ++i)
        a += cf[b0 + i] * __bfloat162float(Yb[(size_t)csr[b0 + i] * 64 + f]);
    rows[w][f] = a;
    __syncthreads();
    float acc = vecf[192 + f];
    for (int k = 0; k < 64; k += 4){
        float4 rv = *(const float4*)&rows[w][k];
        acc += rv.x * w3s[k * 64 + f]       + rv.y * w3s[(k + 1) * 64 + f]
             + rv.z * w3s[(k + 2) * 64 + f] + rv.w * w3s[(k + 3) * 64 + f];
    }
    out[(size_t)n * 64 + f] = acc;
}

// ---------------- launch ----------------

extern "C" void kernel_launch(void* const* d_in, const int* in_sizes, int n_in,
                              void* d_out, int out_size, void* d_ws, size_t ws_size,
                              hipStream_t stream) {
    const void* x  = d_in[0];
    const int*  ei = (const int*)d_in[1];
    float* out = (float*)d_out;

    char* p = (char*)d_ws;
    auto alloc = [&](size_t bytes) -> void* {
        void* r = (void*)p;
        p += (bytes + 255) & ~(size_t)255;
        return r;
    };
    int*   deg      = (int*)  alloc((size_t)N_NODES * 4);
    int*   cursor   = (int*)  alloc((size_t)N_NODES * 4);
    int*   row_ptr  = (int*)  alloc((size_t)(N_NODES + 1) * 4);
    int*   blk      = (int*)  alloc(256 * 4);
    int*   csr      = (int*)  alloc((size_t)E_TOT * 4);
    float* coef     = (float*)alloc((size_t)E_TOT * 4);
    float* inv_sqrt = (float*)alloc((size_t)N_NODES * 4);
    float* a_src    = (float*)alloc((size_t)N_NODES * 2 * 4);
    float* a_dst    = (float*)alloc((size_t)N_NODES * 2 * 4);
    bf16*  W1p      = (bf16*) alloc(16384 * 2);
    bf16*  Wgp      = (bf16*) alloc(16384 * 2);
    float* W3f      = (float*)alloc(4096 * 4);
    float* vecf     = (float*)alloc(512 * 4);
    bf16*  xb       = (bf16*) alloc((size_t)N_NODES * 128 * 2);  // 12.8 MB
    bf16*  XA       = (bf16*) alloc((size_t)N_NODES * 128 * 2);  // 12.8 MB (Xa -> h1 -> X2, in-place)
    bf16*  Y        = (bf16*) alloc((size_t)N_NODES * 64 * 2);   //  6.4 MB
    // total ~40 MB

    const int NB_NODE = (N_NODES + 255) / 256;              // 196
    const int NB_EDGE = (E_TOT + 255) / 256;
    const int NXB     = (N_NODES * 128 + 255) / 256;
    const int NB_CONV = 146 + NXB + NB_NODE;

    k_convert<<<NB_CONV, 256, 0, stream>>>(x, d_in[2], d_in[4], d_in[8],
                                           d_in[3], d_in[7], d_in[9], d_in[5], d_in[6],
                                           W1p, Wgp, W3f, vecf, xb, deg, cursor);
    k_count<<<NB_EDGE, 256, 0, stream>>>(ei, deg);
    k_scanA<<<NB_NODE, 256, 0, stream>>>(deg, row_ptr, blk);
    k_scanB<<<1, 256, 0, stream>>>(blk, NB_NODE);
    k_scanC<<<NB_NODE, 256, 0, stream>>>(row_ptr, blk, deg, inv_sqrt);
    k_fill<<<NB_EDGE, 256, 0, stream>>>(ei, row_ptr, inv_sqrt, cursor, csr, coef);

    k_gather<<<N_NODES / 4, 128, 0, stream>>>(xb, row_ptr, csr, coef, XA);
    k_gemm_mfma<0><<<N_NODES / 16, 512, 0, stream>>>(XA, W1p, vecf, XA);   // h1 = relu(Xa W1 + b1)
    k_gemm_mfma<1><<<N_NODES / 16, 512, 0, stream>>>(XA, Wgp, vecf, XA);   // X2 = h1 Wg (interleaved)
    k_att<<<N_NODES / 4, 256, 0, stream>>>((const unsigned*)XA, vecf, (float2*)a_src, (float2*)a_dst);
    k_gat<<<N_NODES / 4, 256, 0, stream>>>((const unsigned*)XA, row_ptr, csr,
                                           (const float2*)a_src, (const float2*)a_dst,
                                           vecf, Y);
    k_mega3<<<N_NODES / 4, 256, 0, stream>>>(Y, row_ptr, csr, coef, W3f, vecf, out);
}

// Round 12
// 445.705 us; speedup vs baseline: 2.4462x; 1.0823x over previous
//
#include <hip/hip_runtime.h>
#include <hip/hip_bf16.h>
#include <math.h>

#define N_NODES 50000
#define E0      800000
#define E_TOT   (E0 + N_NODES)
#define SCAP    512

using bf16 = __hip_bfloat16;
typedef __attribute__((ext_vector_type(8))) short bfrag;   // 8 bf16 (4 VGPRs)
typedef __attribute__((ext_vector_type(4))) float ffrag;   // 4 fp32 acc

static __device__ __forceinline__ float bfu2f_lo(unsigned u){ return __uint_as_float(u << 16); }
static __device__ __forceinline__ float bfu2f_hi(unsigned u){ return __uint_as_float(u & 0xffff0000u); }

// per-wave dtype detects (one coalesced load + ballot)
static __device__ __forceinline__ int detect_f32(const unsigned* xu){
    int lane = threadIdx.x & 63;
    unsigned ex = (xu[lane] >> 7) & 0xFF;
    return (__ballot(ex < 100 || ex > 140) != 0ULL);
}
static __device__ __forceinline__ int detect_i32(const int* ei){
    int lane = threadIdx.x & 63;
    return (__ballot(ei[2 * lane + 1] != 0) != 0ULL);
}

static __device__ __forceinline__ float ldany(const void* p, int i, int isf32){
    return isf32 ? ((const float*)p)[i] : __bfloat162float(((const bf16*)p)[i]);
}

// ---------------- convert: W1/Wg/W3 -> packed bf16 MFMA frags, vecs->fp32,
// x->bf16, zero deg/cursor — one grid.
// vecf: b1 @0(128), bg @128(64), b3 @192(64), att_s @256(128), att_d @384(128)
// pack(128x128): [ct(8)][kc(4)][L(64)][j(8)] <- W[(kc*32+(L>>4)*8+j)*128 + (ct*16+(L&15))]
// pack(64x64):   [ct(4)][kc(2)][L(64)][j(8)] <- W[(kc*32+(L>>4)*8+j)*64  + (ct*16+(L&15))]
__global__ void k_convert(const void* __restrict__ xv,
                          const void* W1, const void* Wg, const void* W3,
                          const void* b1, const void* bg, const void* b3,
                          const void* as_, const void* ad_,
                          bf16* __restrict__ W1p, bf16* __restrict__ Wgp,
                          bf16* __restrict__ W3p, float* __restrict__ vecf,
                          bf16* __restrict__ xb, int* __restrict__ deg,
                          int* __restrict__ cursor){
    const int NXB = (N_NODES * 128 + 255) / 256;
    int b = blockIdx.x, t = threadIdx.x;
    if (b >= 148 + NXB){
        int i = (b - 148 - NXB) * 256 + t;
        if (i < N_NODES){ deg[i] = 0; cursor[i] = 0; }
        return;
    }
    int isf = detect_f32((const unsigned*)xv);
    if (b >= 148){
        int i = (b - 148) * 256 + t;
        if (i < N_NODES * 128) xb[i] = __float2bfloat16(ldany(xv, i, isf));
        return;
    }
    if (b < 16){                              // W3 pack: 4096 elems
        int dd = b * 256 + t;
        int j  = dd & 7;
        int L  = (dd >> 3) & 63;
        int kc = (dd >> 9) & 1;
        int ct = dd >> 10;
        int k = kc * 32 + ((L >> 4) << 3) + j;
        int n = ct * 16 + (L & 15);
        W3p[dd] = __float2bfloat16(ldany(W3, k * 64 + n, isf));
    }
    else if (b < 18){
        int i = (b - 16) * 256 + t;     // 0..511
        float v;
        if      (i < 128) v = ldany(b1,  i,       isf);
        else if (i < 192) v = ldany(bg,  i - 128, isf);
        else if (i < 256) v = ldany(b3,  i - 192, isf);
        else if (i < 384) v = ldany(as_, i - 256, isf);
        else              v = ldany(ad_, i - 384, isf);
        vecf[i] = v;
    } else {
        int d = (b - 18) * 256 + t;          // 0..16383 per W, two Ws
        const void* Wsrc = (d < 16384) ? W1 : Wg;
        bf16* Wdst = (d < 16384) ? W1p : Wgp;
        int dd = d & 16383;
        int j  = dd & 7;
        int L  = (dd >> 3) & 63;
        int kc = (dd >> 9) & 3;
        int ct = dd >> 11;
        int k = kc * 32 + ((L >> 4) << 3) + j;
        int n = ct * 16 + (L & 15);
        Wdst[dd] = __float2bfloat16(ldany(Wsrc, k * 128 + n, isf));
    }
}

// ---------------- CSR build ----------------

static __device__ __forceinline__ int load_dst(const int* ei, int e, int is32){
    if (e >= E0) return e - E0;
    return is32 ? ei[E0 + e] : (int)((const long long*)ei)[E0 + e];
}
static __device__ __forceinline__ int load_src(const int* ei, int e, int is32){
    if (e >= E0) return e - E0;
    return is32 ? ei[e] : (int)((const long long*)ei)[e];
}

__global__ void k_count(const int* __restrict__ ei, int* __restrict__ deg){
    int is32 = detect_i32(ei);
    int e = blockIdx.x * blockDim.x + threadIdx.x;
    if (e >= E_TOT) return;
    int dst = load_dst(ei, e, is32);
    int src = load_src(ei, e, is32);
    if ((unsigned)dst >= N_NODES || (unsigned)src >= N_NODES) return;
    atomicAdd(&deg[dst], 1);
}

__global__ void k_scanA(const int* __restrict__ deg, int* __restrict__ tmp, int* __restrict__ blk){
    __shared__ int s[256];
    int t = threadIdx.x;
    int i = blockIdx.x * 256 + t;
    int v = (i < N_NODES) ? deg[i] : 0;
    s[t] = v; __syncthreads();
    for (int off = 1; off < 256; off <<= 1){
        int x = (t >= off) ? s[t - off] : 0;
        __syncthreads();
        s[t] += x;
        __syncthreads();
    }
    if (t == 255) blk[blockIdx.x] = s[255];
    if (i < N_NODES) tmp[i] = s[t] - v;
}

__global__ void k_scanB(int* __restrict__ blk, int nb){
    __shared__ int s[256];
    int t = threadIdx.x;
    int v = (t < nb) ? blk[t] : 0;
    s[t] = v; __syncthreads();
    for (int off = 1; off < 256; off <<= 1){
        int x = (t >= off) ? s[t - off] : 0;
        __syncthreads();
        s[t] += x;
        __syncthreads();
    }
    if (t < nb) blk[t] = s[t] - v;
}

__global__ void k_scanC(int* __restrict__ row_ptr, const int* __restrict__ blk,
                        const int* __restrict__ deg, float* __restrict__ inv_sqrt){
    int i = blockIdx.x * blockDim.x + threadIdx.x;
    if (i < N_NODES){
        row_ptr[i] += blk[i >> 8];
        int d = deg[i];
        inv_sqrt[i] = (d > 0) ? rsqrtf((float)d) : 0.0f;
    }
    if (i == 0) row_ptr[N_NODES] = E_TOT;
}

__global__ void k_fill(const int* __restrict__ ei, const int* __restrict__ row_ptr,
                       const float* __restrict__ isq, int* __restrict__ cursor,
                       int* __restrict__ csr_src, float* __restrict__ coef){
    int is32 = detect_i32(ei);
    int e = blockIdx.x * blockDim.x + threadIdx.x;
    if (e >= E_TOT) return;
    int dst = load_dst(ei, e, is32);
    int src = load_src(ei, e, is32);
    if ((unsigned)dst >= N_NODES || (unsigned)src >= N_NODES) return;
    int pos = row_ptr[dst] + atomicAdd(&cursor[dst], 1);
    csr_src[pos] = src;
    coef[pos] = isq[dst] * isq[src];
}

// ---------------- gather: Xa = A_hat x  (proven shape, bf16 out) ----------------
__global__ __launch_bounds__(128, 4) void k_gather(
        const bf16* __restrict__ xb, const int* __restrict__ rp,
        const int* __restrict__ csr, const float* __restrict__ cf,
        bf16* __restrict__ Xa){
    __shared__ int   scsr[SCAP];
    __shared__ float scf[SCAP];
    int n0 = blockIdx.x * 4;
    int j = threadIdx.x;

    int b0 = rp[n0];
    int tot  = rp[n0 + 4] - b0;
    int stot = min(tot, SCAP);
    for (int i = j; i < stot; i += 128){
        scsr[i] = csr[b0 + i];
        scf[i]  = cf[b0 + i];
    }
    __syncthreads();

    #pragma unroll
    for (int r = 0; r < 4; ++r){
        int n = n0 + r;
        float a = 0.f;
        int b = rp[n] - b0, e = rp[n + 1] - b0;
        int elim = min(e, stot);
        for (int i = b; i < elim; ++i)
            a += scf[i] * __bfloat162float(xb[(size_t)scsr[i] * 128 + j]);
        for (int i = max(b, stot); i < e; ++i)
            a += cf[b0 + i] * __bfloat162float(xb[(size_t)csr[b0 + i] * 128 + j]);
        Xa[(size_t)n * 128 + j] = __float2bfloat16(a);
    }
}

// ---------------- MFMA GEMM 128x128: O = A @ Wp [+b1,relu | interleave] ----------------
// 512 thr = 8 waves; block = 16-row tile; wave = col-tile. Layouts HW-verified (m89/m91).
template<int EPI>
__global__ __launch_bounds__(512) void k_gemm_mfma(
        const bf16* __restrict__ A, const bf16* __restrict__ Wp,
        const float* __restrict__ vecf, bf16* __restrict__ O){
    int wid  = threadIdx.x >> 6;
    int lane = threadIdx.x & 63;
    int n0 = blockIdx.x * 16;
    int m = lane & 15, q = lane >> 4;

    const bfrag* Ap = (const bfrag*)(A + (size_t)(n0 + m) * 128);
    const bfrag* Bp = (const bfrag*)Wp + (size_t)wid * 256 + lane;

    ffrag c = {0.f, 0.f, 0.f, 0.f};
    #pragma unroll
    for (int kc = 0; kc < 4; ++kc){
        bfrag af = Ap[kc * 4 + q];
        bfrag bf = Bp[kc * 64];
        c = __builtin_amdgcn_mfma_f32_16x16x32_bf16(af, bf, c, 0, 0, 0);
    }
    __syncthreads();                      // all A reads done -> in-place stores safe

    int col = wid * 16 + m;
    if (EPI == 0){
        float bb = vecf[col];             // b1
        #pragma unroll
        for (int r = 0; r < 4; ++r){
            int row = n0 + q * 4 + r;
            O[(size_t)row * 128 + col] = __float2bfloat16(fmaxf(c[r] + bb, 0.f));
        }
    } else {                              // interleaved X2: slot (f*2 + head)
        int f = col & 63, h = col >> 6;
        #pragma unroll
        for (int r = 0; r < 4; ++r){
            int row = n0 + q * 4 + r;
            O[(size_t)row * 128 + f * 2 + h] = __float2bfloat16(c[r]);
        }
    }
}

// ---------------- MFMA GEMM 64x64: Z = Y @ W3p (bf16 out, no bias) ----------------
// 256 thr = 4 waves; block = 16-row tile; wave = col-tile (4 tiles of 16).
__global__ __launch_bounds__(256) void k_gemm_z(
        const bf16* __restrict__ Y, const bf16* __restrict__ W3p,
        bf16* __restrict__ Z){
    int wid  = threadIdx.x >> 6;
    int lane = threadIdx.x & 63;
    int n0 = blockIdx.x * 16;
    int m = lane & 15, q = lane >> 4;

    const bfrag* Ap = (const bfrag*)(Y + (size_t)(n0 + m) * 64);   // +i covers k [i*8,i*8+8)
    const bfrag* Bp = (const bfrag*)W3p + (size_t)wid * 128 + lane; // [ct][kc][lane]

    ffrag c = {0.f, 0.f, 0.f, 0.f};
    #pragma unroll
    for (int kc = 0; kc < 2; ++kc){
        bfrag af = Ap[kc * 4 + q];
        bfrag bf = Bp[kc * 64];
        c = __builtin_amdgcn_mfma_f32_16x16x32_bf16(af, bf, c, 0, 0, 0);
    }
    int col = wid * 16 + m;
    #pragma unroll
    for (int r = 0; r < 4; ++r){
        int row = n0 + q * 4 + r;
        Z[(size_t)row * 64 + col] = __float2bfloat16(c[r]);
    }
}

// ---------------- att logits: per-node wave reduce over interleaved X2 ----------------
__global__ __launch_bounds__(256) void k_att(
        const unsigned* __restrict__ X2u, const float* __restrict__ vecf,
        float2* __restrict__ a_src, float2* __restrict__ a_dst){
    int n = blockIdx.x * 4 + (threadIdx.x >> 6);
    int l = threadIdx.x & 63;
    unsigned v = X2u[(size_t)n * 64 + l];
    float x0 = bfu2f_lo(v), x1 = bfu2f_hi(v);
    float s0 = x0 * vecf[256 + l], s1 = x1 * vecf[320 + l];
    float d0 = x0 * vecf[384 + l], d1 = x1 * vecf[448 + l];
    for (int off = 32; off; off >>= 1){
        s0 += __shfl_down(s0, off, 64);  s1 += __shfl_down(s1, off, 64);
        d0 += __shfl_down(d0, off, 64);  d1 += __shfl_down(d1, off, 64);
    }
    if (l == 0){
        a_src[n] = make_float2(s0, s1);
        a_dst[n] = make_float2(d0, d1);
    }
}

// ---------------- GAT aggregate: softmax (no-max; logits bounded) + mean + bg + ELU ----
__global__ __launch_bounds__(256) void k_gat(
        const unsigned* __restrict__ X2u, const int* __restrict__ rp,
        const int* __restrict__ csr, const float2* __restrict__ a_src,
        const float2* __restrict__ a_dst, const float* __restrict__ vecf,
        bf16* __restrict__ Y){
    __shared__ int scsr[SCAP];
    int n0 = blockIdx.x * 4;
    int b0 = rp[n0];
    int tot  = rp[n0 + 4] - b0;
    int stot = min(tot, SCAP);
    for (int i = threadIdx.x; i < stot; i += 256) scsr[i] = csr[b0 + i];
    __syncthreads();

    int n = n0 + (threadIdx.x >> 6);
    int f = threadIdx.x & 63;
    float2 ad = a_dst[n];
    float l0 = 0.f, l1 = 0.f, o0 = 0.f, o1 = 0.f;
    int b = rp[n] - b0, e = rp[n + 1] - b0;
    int elim = min(e, stot);
    for (int i = b; i < elim; ++i){
        int s = scsr[i];
        float2 av = a_src[s];
        unsigned v = X2u[(size_t)s * 64 + f];
        float e0 = av.x + ad.x, e1 = av.y + ad.y;
        e0 = (e0 > 0.f) ? e0 : 0.2f * e0;
        e1 = (e1 > 0.f) ? e1 : 0.2f * e1;
        float p0 = __expf(e0), p1 = __expf(e1);
        l0 += p0;  o0 += p0 * bfu2f_lo(v);
        l1 += p1;  o1 += p1 * bfu2f_hi(v);
    }
    for (int i = max(b, stot); i < e; ++i){
        int s = csr[b0 + i];
        float2 av = a_src[s];
        unsigned v = X2u[(size_t)s * 64 + f];
        float e0 = av.x + ad.x, e1 = av.y + ad.y;
        e0 = (e0 > 0.f) ? e0 : 0.2f * e0;
        e1 = (e1 > 0.f) ? e1 : 0.2f * e1;
        float p0 = __expf(e0), p1 = __expf(e1);
        l0 += p0;  o0 += p0 * bfu2f_lo(v);
        l1 += p1;  o1 += p1 * bfu2f_hi(v);
    }
    float val = 0.5f * (o0 / l0 + o1 / l1) + vecf[128 + f];
    val = (val > 0.f) ? val : expm1f(val);
    Y[(size_t)n * 64 + f] = __float2bfloat16(val);
}

// ---------------- gather_out: out = A_hat Z + b3 (fp32 out) ----------------
__global__ __launch_bounds__(256) void k_gather_out(
        const bf16* __restrict__ Z, const int* __restrict__ rp,
        const int* __restrict__ csr, const float* __restrict__ cf,
        const float* __restrict__ vecf, float* __restrict__ out){
    __shared__ int   scsr[SCAP];
    __shared__ float scf[SCAP];
    int n0 = blockIdx.x * 4;
    int b0 = rp[n0];
    int tot  = rp[n0 + 4] - b0;
    int stot = min(tot, SCAP);
    for (int i = threadIdx.x; i < stot; i += 256){
        scsr[i] = csr[b0 + i];
        scf[i]  = cf[b0 + i];
    }
    __syncthreads();

    int w = threadIdx.x >> 6, f = threadIdx.x & 63;
    int n = n0 + w;
    float a = vecf[192 + f];                   // b3
    int b = rp[n] - b0, e = rp[n + 1] - b0;
    int elim = min(e, stot);
    for (int i = b; i < elim; ++i)
        a += scf[i] * __bfloat162float(Z[(size_t)scsr[i] * 64 + f]);
    for (int i = max(b, stot); i < e; ++i)     // fallback
        a += cf[b0 + i] * __bfloat162float(Z[(size_t)csr[b0 + i] * 64 + f]);
    out[(size_t)n * 64 + f] = a;
}

// ---------------- launch ----------------

extern "C" void kernel_launch(void* const* d_in, const int* in_sizes, int n_in,
                              void* d_out, int out_size, void* d_ws, size_t ws_size,
                              hipStream_t stream) {
    const void* x  = d_in[0];
    const int*  ei = (const int*)d_in[1];
    float* out = (float*)d_out;

    char* p = (char*)d_ws;
    auto alloc = [&](size_t bytes) -> void* {
        void* r = (void*)p;
        p += (bytes + 255) & ~(size_t)255;
        return r;
    };
    int*   deg      = (int*)  alloc((size_t)N_NODES * 4);
    int*   cursor   = (int*)  alloc((size_t)N_NODES * 4);
    int*   row_ptr  = (int*)  alloc((size_t)(N_NODES + 1) * 4);
    int*   blk      = (int*)  alloc(256 * 4);
    int*   csr      = (int*)  alloc((size_t)E_TOT * 4);
    float* coef     = (float*)alloc((size_t)E_TOT * 4);
    float* inv_sqrt = (float*)alloc((size_t)N_NODES * 4);
    float* a_src    = (float*)alloc((size_t)N_NODES * 2 * 4);
    float* a_dst    = (float*)alloc((size_t)N_NODES * 2 * 4);
    bf16*  W1p      = (bf16*) alloc(16384 * 2);
    bf16*  Wgp      = (bf16*) alloc(16384 * 2);
    bf16*  W3p      = (bf16*) alloc(4096 * 2);
    float* vecf     = (float*)alloc(512 * 4);
    bf16*  xb       = (bf16*) alloc((size_t)N_NODES * 128 * 2);  // 12.8 MB; dead after k_gather
    bf16*  XA       = (bf16*) alloc((size_t)N_NODES * 128 * 2);  // 12.8 MB (Xa -> h1 -> X2)
    bf16*  Y        = (bf16*) alloc((size_t)N_NODES * 64 * 2);   //  6.4 MB
    bf16*  Z        = xb;                                        // alias: Y@W3, layer-3 only
    // total ~40 MB

    const int NB_NODE = (N_NODES + 255) / 256;              // 196
    const int NB_EDGE = (E_TOT + 255) / 256;
    const int NXB     = (N_NODES * 128 + 255) / 256;
    const int NB_CONV = 148 + NXB + NB_NODE;

    k_convert<<<NB_CONV, 256, 0, stream>>>(x, d_in[2], d_in[4], d_in[8],
                                           d_in[3], d_in[7], d_in[9], d_in[5], d_in[6],
                                           W1p, Wgp, W3p, vecf, xb, deg, cursor);
    k_count<<<NB_EDGE, 256, 0, stream>>>(ei, deg);
    k_scanA<<<NB_NODE, 256, 0, stream>>>(deg, row_ptr, blk);
    k_scanB<<<1, 256, 0, stream>>>(blk, NB_NODE);
    k_scanC<<<NB_NODE, 256, 0, stream>>>(row_ptr, blk, deg, inv_sqrt);
    k_fill<<<NB_EDGE, 256, 0, stream>>>(ei, row_ptr, inv_sqrt, cursor, csr, coef);

    k_gather<<<N_NODES / 4, 128, 0, stream>>>(xb, row_ptr, csr, coef, XA);
    k_gemm_mfma<0><<<N_NODES / 16, 512, 0, stream>>>(XA, W1p, vecf, XA);   // h1 = relu(Xa W1 + b1)
    k_gemm_mfma<1><<<N_NODES / 16, 512, 0, stream>>>(XA, Wgp, vecf, XA);   // X2 = h1 Wg (interleaved)
    k_att<<<N_NODES / 4, 256, 0, stream>>>((const unsigned*)XA, vecf, (float2*)a_src, (float2*)a_dst);
    k_gat<<<N_NODES / 4, 256, 0, stream>>>((const unsigned*)XA, row_ptr, csr,
                                           (const float2*)a_src, (const float2*)a_dst,
                                           vecf, Y);
    k_gemm_z<<<N_NODES / 16 + 1, 256, 0, stream>>>(Y, W3p, Z);             // Z = Y W3 (grid covers 50000: 3125+1 pads)
    k_gather_out<<<N_NODES / 4, 256, 0, stream>>>(Z, row_ptr, csr, coef, vecf, out);
}

// Round 13
// 350.222 us; speedup vs baseline: 3.1131x; 1.2726x over previous
//
#include <hip/hip_runtime.h>
#include <hip/hip_bf16.h>
#include <math.h>

#define N_NODES 50000
#define E0      800000
#define E_TOT   (E0 + N_NODES)
#define SCAP    512

using bf16 = __hip_bfloat16;
typedef __attribute__((ext_vector_type(8))) short bfrag;   // 8 bf16 (4 VGPRs)
typedef __attribute__((ext_vector_type(4))) float ffrag;   // 4 fp32 acc

static __device__ __forceinline__ float bfu2f_lo(unsigned u){ return __uint_as_float(u << 16); }
static __device__ __forceinline__ float bfu2f_hi(unsigned u){ return __uint_as_float(u & 0xffff0000u); }

static __device__ __forceinline__ unsigned packbf(float a, float b){
    bf16 x = __float2bfloat16(a), y = __float2bfloat16(b);
    unsigned short ux = *reinterpret_cast<unsigned short*>(&x);
    unsigned short uy = *reinterpret_cast<unsigned short*>(&y);
    return ((unsigned)uy << 16) | ux;
}

// per-wave dtype detects (one coalesced load + ballot)
static __device__ __forceinline__ int detect_f32(const unsigned* xu){
    int lane = threadIdx.x & 63;
    unsigned ex = (xu[lane] >> 7) & 0xFF;
    return (__ballot(ex < 100 || ex > 140) != 0ULL);
}
static __device__ __forceinline__ int detect_i32(const int* ei){
    int lane = threadIdx.x & 63;
    return (__ballot(ei[2 * lane + 1] != 0) != 0ULL);
}

static __device__ __forceinline__ float ldany(const void* p, int i, int isf32){
    return isf32 ? ((const float*)p)[i] : __bfloat162float(((const bf16*)p)[i]);
}

// ---------------- convert: W1/Wg/W3 -> packed bf16 MFMA frags, vecs->fp32,
// x->bf16, zero deg/cursor — one grid.
// vecf: b1 @0(128), bg @128(64), b3 @192(64), att_s @256(128), att_d @384(128)
__global__ void k_convert(const void* __restrict__ xv,
                          const void* W1, const void* Wg, const void* W3,
                          const void* b1, const void* bg, const void* b3,
                          const void* as_, const void* ad_,
                          bf16* __restrict__ W1p, bf16* __restrict__ Wgp,
                          bf16* __restrict__ W3p, float* __restrict__ vecf,
                          bf16* __restrict__ xb, int* __restrict__ deg,
                          int* __restrict__ cursor){
    const int NXB = (N_NODES * 128 + 255) / 256;
    int b = blockIdx.x, t = threadIdx.x;
    if (b >= 148 + NXB){
        int i = (b - 148 - NXB) * 256 + t;
        if (i < N_NODES){ deg[i] = 0; cursor[i] = 0; }
        return;
    }
    int isf = detect_f32((const unsigned*)xv);
    if (b >= 148){
        int i = (b - 148) * 256 + t;
        if (i < N_NODES * 128) xb[i] = __float2bfloat16(ldany(xv, i, isf));
        return;
    }
    if (b < 16){                              // W3 pack: 4096 elems
        int dd = b * 256 + t;
        int j  = dd & 7;
        int L  = (dd >> 3) & 63;
        int kc = (dd >> 9) & 1;
        int ct = dd >> 10;
        int k = kc * 32 + ((L >> 4) << 3) + j;
        int n = ct * 16 + (L & 15);
        W3p[dd] = __float2bfloat16(ldany(W3, k * 64 + n, isf));
    }
    else if (b < 18){
        int i = (b - 16) * 256 + t;     // 0..511
        float v;
        if      (i < 128) v = ldany(b1,  i,       isf);
        else if (i < 192) v = ldany(bg,  i - 128, isf);
        else if (i < 256) v = ldany(b3,  i - 192, isf);
        else if (i < 384) v = ldany(as_, i - 256, isf);
        else              v = ldany(ad_, i - 384, isf);
        vecf[i] = v;
    } else {
        int d = (b - 18) * 256 + t;          // 0..16383 per W, two Ws
        const void* Wsrc = (d < 16384) ? W1 : Wg;
        bf16* Wdst = (d < 16384) ? W1p : Wgp;
        int dd = d & 16383;
        int j  = dd & 7;
        int L  = (dd >> 3) & 63;
        int kc = (dd >> 9) & 3;
        int ct = dd >> 11;
        int k = kc * 32 + ((L >> 4) << 3) + j;
        int n = ct * 16 + (L & 15);
        Wdst[dd] = __float2bfloat16(ldany(Wsrc, k * 128 + n, isf));
    }
}

// ---------------- CSR build ----------------

static __device__ __forceinline__ int load_dst(const int* ei, int e, int is32){
    if (e >= E0) return e - E0;
    return is32 ? ei[E0 + e] : (int)((const long long*)ei)[E0 + e];
}
static __device__ __forceinline__ int load_src(const int* ei, int e, int is32){
    if (e >= E0) return e - E0;
    return is32 ? ei[e] : (int)((const long long*)ei)[e];
}

__global__ void k_count(const int* __restrict__ ei, int* __restrict__ deg){
    int is32 = detect_i32(ei);
    int e = blockIdx.x * blockDim.x + threadIdx.x;
    if (e >= E_TOT) return;
    int dst = load_dst(ei, e, is32);
    int src = load_src(ei, e, is32);
    if ((unsigned)dst >= N_NODES || (unsigned)src >= N_NODES) return;
    atomicAdd(&deg[dst], 1);
}

__global__ void k_scanA(const int* __restrict__ deg, int* __restrict__ tmp, int* __restrict__ blk){
    __shared__ int s[256];
    int t = threadIdx.x;
    int i = blockIdx.x * 256 + t;
    int v = (i < N_NODES) ? deg[i] : 0;
    s[t] = v; __syncthreads();
    for (int off = 1; off < 256; off <<= 1){
        int x = (t >= off) ? s[t - off] : 0;
        __syncthreads();
        s[t] += x;
        __syncthreads();
    }
    if (t == 255) blk[blockIdx.x] = s[255];
    if (i < N_NODES) tmp[i] = s[t] - v;
}

__global__ void k_scanB(int* __restrict__ blk, int nb){
    __shared__ int s[256];
    int t = threadIdx.x;
    int v = (t < nb) ? blk[t] : 0;
    s[t] = v; __syncthreads();
    for (int off = 1; off < 256; off <<= 1){
        int x = (t >= off) ? s[t - off] : 0;
        __syncthreads();
        s[t] += x;
        __syncthreads();
    }
    if (t < nb) blk[t] = s[t] - v;
}

__global__ void k_scanC(int* __restrict__ row_ptr, const int* __restrict__ blk,
                        const int* __restrict__ deg, float* __restrict__ inv_sqrt){
    int i = blockIdx.x * blockDim.x + threadIdx.x;
    if (i < N_NODES){
        row_ptr[i] += blk[i >> 8];
        int d = deg[i];
        inv_sqrt[i] = (d > 0) ? rsqrtf((float)d) : 0.0f;
    }
    if (i == 0) row_ptr[N_NODES] = E_TOT;
}

__global__ void k_fill(const int* __restrict__ ei, const int* __restrict__ row_ptr,
                       const float* __restrict__ isq, int* __restrict__ cursor,
                       int* __restrict__ csr_src, float* __restrict__ coef){
    int is32 = detect_i32(ei);
    int e = blockIdx.x * blockDim.x + threadIdx.x;
    if (e >= E_TOT) return;
    int dst = load_dst(ei, e, is32);
    int src = load_src(ei, e, is32);
    if ((unsigned)dst >= N_NODES || (unsigned)src >= N_NODES) return;
    int pos = row_ptr[dst] + atomicAdd(&cursor[dst], 1);
    csr_src[pos] = src;
    coef[pos] = isq[dst] * isq[src];
}

// ---------------- gather: Xa = A_hat x — node-per-wave, ushort2/lane ----------------
// 256 thr = 4 waves; wave w owns node n0+w (chain = deg(n) ~17, not 68).
// Lane covers features (2l, 2l+1): one 4B load per edge covers the full 256B row per wave.
__global__ __launch_bounds__(256, 2) void k_gather(
        const ushort2* __restrict__ xb2, const int* __restrict__ rp,
        const int* __restrict__ csr, const float* __restrict__ cf,
        unsigned* __restrict__ Xa){
    __shared__ int   scsr[SCAP];
    __shared__ float scf[SCAP];
    int n0 = blockIdx.x * 4;
    int b0 = rp[n0];
    int tot  = rp[n0 + 4] - b0;
    int stot = min(tot, SCAP);
    for (int i = threadIdx.x; i < stot; i += 256){
        scsr[i] = csr[b0 + i];
        scf[i]  = cf[b0 + i];
    }
    __syncthreads();

    int w = threadIdx.x >> 6, l = threadIdx.x & 63;
    int n = n0 + w;
    float a0 = 0.f, a1 = 0.f;
    int b = rp[n] - b0, e = rp[n + 1] - b0;
    int elim = min(e, stot);
    #pragma unroll 4
    for (int i = b; i < elim; ++i){
        int s = scsr[i];
        float c = scf[i];
        ushort2 v = xb2[(size_t)s * 64 + l];
        a0 += c * __uint_as_float((unsigned)v.x << 16);
        a1 += c * __uint_as_float((unsigned)v.y << 16);
    }
    for (int i = max(b, stot); i < e; ++i){    // fallback (pathological degree)
        int s = csr[b0 + i];
        float c = cf[b0 + i];
        ushort2 v = xb2[(size_t)s * 64 + l];
        a0 += c * __uint_as_float((unsigned)v.x << 16);
        a1 += c * __uint_as_float((unsigned)v.y << 16);
    }
    Xa[(size_t)n * 64 + l] = packbf(a0, a1);   // features 2l, 2l+1 (row-major, packed)
}

// ---------------- MFMA GEMM 128x128: O = A @ Wp [+b1,relu | interleave] ----------------
template<int EPI>
__global__ __launch_bounds__(512) void k_gemm_mfma(
        const bf16* __restrict__ A, const bf16* __restrict__ Wp,
        const float* __restrict__ vecf, bf16* __restrict__ O){
    int wid  = threadIdx.x >> 6;
    int lane = threadIdx.x & 63;
    int n0 = blockIdx.x * 16;
    int m = lane & 15, q = lane >> 4;

    const bfrag* Ap = (const bfrag*)(A + (size_t)(n0 + m) * 128);
    const bfrag* Bp = (const bfrag*)Wp + (size_t)wid * 256 + lane;

    ffrag c = {0.f, 0.f, 0.f, 0.f};
    #pragma unroll
    for (int kc = 0; kc < 4; ++kc){
        bfrag af = Ap[kc * 4 + q];
        bfrag bf = Bp[kc * 64];
        c = __builtin_amdgcn_mfma_f32_16x16x32_bf16(af, bf, c, 0, 0, 0);
    }
    __syncthreads();                      // all A reads done -> in-place stores safe

    int col = wid * 16 + m;
    if (EPI == 0){
        float bb = vecf[col];             // b1
        #pragma unroll
        for (int r = 0; r < 4; ++r){
            int row = n0 + q * 4 + r;
            O[(size_t)row * 128 + col] = __float2bfloat16(fmaxf(c[r] + bb, 0.f));
        }
    } else {                              // interleaved X2: slot (f*2 + head)
        int f = col & 63, h = col >> 6;
        #pragma unroll
        for (int r = 0; r < 4; ++r){
            int row = n0 + q * 4 + r;
            O[(size_t)row * 128 + f * 2 + h] = __float2bfloat16(c[r]);
        }
    }
}

// ---------------- MFMA GEMM 64x64: Z = Y @ W3p (bf16 out, no bias) ----------------
__global__ __launch_bounds__(256) void k_gemm_z(
        const bf16* __restrict__ Y, const bf16* __restrict__ W3p,
        bf16* __restrict__ Z){
    int wid  = threadIdx.x >> 6;
    int lane = threadIdx.x & 63;
    int n0 = blockIdx.x * 16;
    int m = lane & 15, q = lane >> 4;

    const bfrag* Ap = (const bfrag*)(Y + (size_t)(n0 + m) * 64);
    const bfrag* Bp = (const bfrag*)W3p + (size_t)wid * 128 + lane;

    ffrag c = {0.f, 0.f, 0.f, 0.f};
    #pragma unroll
    for (int kc = 0; kc < 2; ++kc){
        bfrag af = Ap[kc * 4 + q];
        bfrag bf = Bp[kc * 64];
        c = __builtin_amdgcn_mfma_f32_16x16x32_bf16(af, bf, c, 0, 0, 0);
    }
    int col = wid * 16 + m;
    #pragma unroll
    for (int r = 0; r < 4; ++r){
        int row = n0 + q * 4 + r;
        Z[(size_t)row * 64 + col] = __float2bfloat16(c[r]);
    }
}

// ---------------- att logits: per-node wave reduce over interleaved X2 ----------------
__global__ __launch_bounds__(256) void k_att(
        const unsigned* __restrict__ X2u, const float* __restrict__ vecf,
        float2* __restrict__ a_src, float2* __restrict__ a_dst){
    int n = blockIdx.x * 4 + (threadIdx.x >> 6);
    int l = threadIdx.x & 63;
    unsigned v = X2u[(size_t)n * 64 + l];
    float x0 = bfu2f_lo(v), x1 = bfu2f_hi(v);
    float s0 = x0 * vecf[256 + l], s1 = x1 * vecf[320 + l];
    float d0 = x0 * vecf[384 + l], d1 = x1 * vecf[448 + l];
    for (int off = 32; off; off >>= 1){
        s0 += __shfl_down(s0, off, 64);  s1 += __shfl_down(s1, off, 64);
        d0 += __shfl_down(d0, off, 64);  d1 += __shfl_down(d1, off, 64);
    }
    if (l == 0){
        a_src[n] = make_float2(s0, s1);
        a_dst[n] = make_float2(d0, d1);
    }
}

// ---------------- GAT aggregate: softmax (no-max; logits bounded) + mean + bg + ELU ----
__global__ __launch_bounds__(256) void k_gat(
        const unsigned* __restrict__ X2u, const int* __restrict__ rp,
        const int* __restrict__ csr, const float2* __restrict__ a_src,
        const float2* __restrict__ a_dst, const float* __restrict__ vecf,
        bf16* __restrict__ Y){
    __shared__ int scsr[SCAP];
    int n0 = blockIdx.x * 4;
    int b0 = rp[n0];
    int tot  = rp[n0 + 4] - b0;
    int stot = min(tot, SCAP);
    for (int i = threadIdx.x; i < stot; i += 256) scsr[i] = csr[b0 + i];
    __syncthreads();

    int n = n0 + (threadIdx.x >> 6);
    int f = threadIdx.x & 63;
    float2 ad = a_dst[n];
    float l0 = 0.f, l1 = 0.f, o0 = 0.f, o1 = 0.f;
    int b = rp[n] - b0, e = rp[n + 1] - b0;
    int elim = min(e, stot);
    #pragma unroll 2
    for (int i = b; i < elim; ++i){
        int s = scsr[i];
        float2 av = a_src[s];
        unsigned v = X2u[(size_t)s * 64 + f];
        float e0 = av.x + ad.x, e1 = av.y + ad.y;
        e0 = (e0 > 0.f) ? e0 : 0.2f * e0;
        e1 = (e1 > 0.f) ? e1 : 0.2f * e1;
        float p0 = __expf(e0), p1 = __expf(e1);
        l0 += p0;  o0 += p0 * bfu2f_lo(v);
        l1 += p1;  o1 += p1 * bfu2f_hi(v);
    }
    for (int i = max(b, stot); i < e; ++i){
        int s = csr[b0 + i];
        float2 av = a_src[s];
        unsigned v = X2u[(size_t)s * 64 + f];
        float e0 = av.x + ad.x, e1 = av.y + ad.y;
        e0 = (e0 > 0.f) ? e0 : 0.2f * e0;
        e1 = (e1 > 0.f) ? e1 : 0.2f * e1;
        float p0 = __expf(e0), p1 = __expf(e1);
        l0 += p0;  o0 += p0 * bfu2f_lo(v);
        l1 += p1;  o1 += p1 * bfu2f_hi(v);
    }
    float val = 0.5f * (o0 / l0 + o1 / l1) + vecf[128 + f];
    val = (val > 0.f) ? val : expm1f(val);
    Y[(size_t)n * 64 + f] = __float2bfloat16(val);
}

// ---------------- gather_out: out = A_hat Z + b3 (fp32 out) ----------------
__global__ __launch_bounds__(256) void k_gather_out(
        const bf16* __restrict__ Z, const int* __restrict__ rp,
        const int* __restrict__ csr, const float* __restrict__ cf,
        const float* __restrict__ vecf, float* __restrict__ out){
    __shared__ int   scsr[SCAP];
    __shared__ float scf[SCAP];
    int n0 = blockIdx.x * 4;
    int b0 = rp[n0];
    int tot  = rp[n0 + 4] - b0;
    int stot = min(tot, SCAP);
    for (int i = threadIdx.x; i < stot; i += 256){
        scsr[i] = csr[b0 + i];
        scf[i]  = cf[b0 + i];
    }
    __syncthreads();

    int w = threadIdx.x >> 6, f = threadIdx.x & 63;
    int n = n0 + w;
    float a = vecf[192 + f];                   // b3
    int b = rp[n] - b0, e = rp[n + 1] - b0;
    int elim = min(e, stot);
    #pragma unroll 4
    for (int i = b; i < elim; ++i)
        a += scf[i] * __bfloat162float(Z[(size_t)scsr[i] * 64 + f]);
    for (int i = max(b, stot); i < e; ++i)     // fallback
        a += cf[b0 + i] * __bfloat162float(Z[(size_t)csr[b0 + i] * 64 + f]);
    out[(size_t)n * 64 + f] = a;
}

// ---------------- launch ----------------

extern "C" void kernel_launch(void* const* d_in, const int* in_sizes, int n_in,
                              void* d_out, int out_size, void* d_ws, size_t ws_size,
                              hipStream_t stream) {
    const void* x  = d_in[0];
    const int*  ei = (const int*)d_in[1];
    float* out = (float*)d_out;

    char* p = (char*)d_ws;
    auto alloc = [&](size_t bytes) -> void* {
        void* r = (void*)p;
        p += (bytes + 255) & ~(size_t)255;
        return r;
    };
    int*   deg      = (int*)  alloc((size_t)N_NODES * 4);
    int*   cursor   = (int*)  alloc((size_t)N_NODES * 4);
    int*   row_ptr  = (int*)  alloc((size_t)(N_NODES + 1) * 4);
    int*   blk      = (int*)  alloc(256 * 4);
    int*   csr      = (int*)  alloc((size_t)E_TOT * 4);
    float* coef     = (float*)alloc((size_t)E_TOT * 4);
    float* inv_sqrt = (float*)alloc((size_t)N_NODES * 4);
    float* a_src    = (float*)alloc((size_t)N_NODES * 2 * 4);
    float* a_dst    = (float*)alloc((size_t)N_NODES * 2 * 4);
    bf16*  W1p      = (bf16*) alloc(16384 * 2);
    bf16*  Wgp      = (bf16*) alloc(16384 * 2);
    bf16*  W3p      = (bf16*) alloc(4096 * 2);
    float* vecf     = (float*)alloc(512 * 4);
    bf16*  xb       = (bf16*) alloc((size_t)N_NODES * 128 * 2);  // 12.8 MB; dead after k_gather
    bf16*  XA       = (bf16*) alloc((size_t)N_NODES * 128 * 2);  // 12.8 MB (Xa -> h1 -> X2)
    bf16*  Y        = (bf16*) alloc((size_t)N_NODES * 64 * 2);   //  6.4 MB
    bf16*  Z        = xb;                                        // alias: Y@W3, layer-3 only
    // total ~40 MB

    const int NB_NODE = (N_NODES + 255) / 256;              // 196
    const int NB_EDGE = (E_TOT + 255) / 256;
    const int NXB     = (N_NODES * 128 + 255) / 256;
    const int NB_CONV = 148 + NXB + NB_NODE;

    k_convert<<<NB_CONV, 256, 0, stream>>>(x, d_in[2], d_in[4], d_in[8],
                                           d_in[3], d_in[7], d_in[9], d_in[5], d_in[6],
                                           W1p, Wgp, W3p, vecf, xb, deg, cursor);
    k_count<<<NB_EDGE, 256, 0, stream>>>(ei, deg);
    k_scanA<<<NB_NODE, 256, 0, stream>>>(deg, row_ptr, blk);
    k_scanB<<<1, 256, 0, stream>>>(blk, NB_NODE);
    k_scanC<<<NB_NODE, 256, 0, stream>>>(row_ptr, blk, deg, inv_sqrt);
    k_fill<<<NB_EDGE, 256, 0, stream>>>(ei, row_ptr, inv_sqrt, cursor, csr, coef);

    k_gather<<<N_NODES / 4, 256, 0, stream>>>((const ushort2*)xb, row_ptr, csr, coef,
                                              (unsigned*)XA);
    k_gemm_mfma<0><<<N_NODES / 16, 512, 0, stream>>>(XA, W1p, vecf, XA);   // h1 = relu(Xa W1 + b1)
    k_gemm_mfma<1><<<N_NODES / 16, 512, 0, stream>>>(XA, Wgp, vecf, XA);   // X2 = h1 Wg (interleaved)
    k_att<<<N_NODES / 4, 256, 0, stream>>>((const unsigned*)XA, vecf, (float2*)a_src, (float2*)a_dst);
    k_gat<<<N_NODES / 4, 256, 0, stream>>>((const unsigned*)XA, row_ptr, csr,
                                           (const float2*)a_src, (const float2*)a_dst,
                                           vecf, Y);
    k_gemm_z<<<N_NODES / 16, 256, 0, stream>>>(Y, W3p, Z);                 // Z = Y W3
    k_gather_out<<<N_NODES / 4, 256, 0, stream>>>(Z, row_ptr, csr, coef, vecf, out);
}

// Round 14
// 335.927 us; speedup vs baseline: 3.2456x; 1.0426x over previous
//
#include <hip/hip_runtime.h>
#include <hip/hip_bf16.h>
#include <math.h>

#define N_NODES 50000
#define E0      800000
#define E_TOT   (E0 + N_NODES)
#define SCAP    512

using bf16 = __hip_bfloat16;
typedef __attribute__((ext_vector_type(8))) short bfrag;   // 8 bf16 (4 VGPRs)
typedef __attribute__((ext_vector_type(4))) float ffrag;   // 4 fp32 acc

static __device__ __forceinline__ float bfu2f_lo(unsigned u){ return __uint_as_float(u << 16); }
static __device__ __forceinline__ float bfu2f_hi(unsigned u){ return __uint_as_float(u & 0xffff0000u); }

static __device__ __forceinline__ unsigned packbf(float a, float b){
    bf16 x = __float2bfloat16(a), y = __float2bfloat16(b);
    unsigned short ux = *reinterpret_cast<unsigned short*>(&x);
    unsigned short uy = *reinterpret_cast<unsigned short*>(&y);
    return ((unsigned)uy << 16) | ux;
}

// per-wave dtype detects (one coalesced load + ballot)
static __device__ __forceinline__ int detect_f32(const unsigned* xu){
    int lane = threadIdx.x & 63;
    unsigned ex = (xu[lane] >> 7) & 0xFF;
    return (__ballot(ex < 100 || ex > 140) != 0ULL);
}
static __device__ __forceinline__ int detect_i32(const int* ei){
    int lane = threadIdx.x & 63;
    return (__ballot(ei[2 * lane + 1] != 0) != 0ULL);
}

static __device__ __forceinline__ float ldany(const void* p, int i, int isf32){
    return isf32 ? ((const float*)p)[i] : __bfloat162float(((const bf16*)p)[i]);
}

// ---------------- convert: W1/Wg/W3 -> packed bf16 MFMA frags, vecs->fp32,
// x->bf16, zero deg/cursor — one grid.
// vecf: b1 @0(128), bg @128(64), b3 @192(64), att_s @256(128), att_d @384(128)
__global__ void k_convert(const void* __restrict__ xv,
                          const void* W1, const void* Wg, const void* W3,
                          const void* b1, const void* bg, const void* b3,
                          const void* as_, const void* ad_,
                          bf16* __restrict__ W1p, bf16* __restrict__ Wgp,
                          bf16* __restrict__ W3p, float* __restrict__ vecf,
                          bf16* __restrict__ xb, int* __restrict__ deg,
                          int* __restrict__ cursor){
    const int NXB = (N_NODES * 128 + 255) / 256;
    int b = blockIdx.x, t = threadIdx.x;
    if (b >= 148 + NXB){
        int i = (b - 148 - NXB) * 256 + t;
        if (i < N_NODES){ deg[i] = 0; cursor[i] = 0; }
        return;
    }
    int isf = detect_f32((const unsigned*)xv);
    if (b >= 148){
        int i = (b - 148) * 256 + t;
        if (i < N_NODES * 128) xb[i] = __float2bfloat16(ldany(xv, i, isf));
        return;
    }
    if (b < 16){                              // W3 pack: 4096 elems
        int dd = b * 256 + t;
        int j  = dd & 7;
        int L  = (dd >> 3) & 63;
        int kc = (dd >> 9) & 1;
        int ct = dd >> 10;
        int k = kc * 32 + ((L >> 4) << 3) + j;
        int n = ct * 16 + (L & 15);
        W3p[dd] = __float2bfloat16(ldany(W3, k * 64 + n, isf));
    }
    else if (b < 18){
        int i = (b - 16) * 256 + t;     // 0..511
        float v;
        if      (i < 128) v = ldany(b1,  i,       isf);
        else if (i < 192) v = ldany(bg,  i - 128, isf);
        else if (i < 256) v = ldany(b3,  i - 192, isf);
        else if (i < 384) v = ldany(as_, i - 256, isf);
        else              v = ldany(ad_, i - 384, isf);
        vecf[i] = v;
    } else {
        int d = (b - 18) * 256 + t;          // 0..16383 per W, two Ws
        const void* Wsrc = (d < 16384) ? W1 : Wg;
        bf16* Wdst = (d < 16384) ? W1p : Wgp;
        int dd = d & 16383;
        int j  = dd & 7;
        int L  = (dd >> 3) & 63;
        int kc = (dd >> 9) & 3;
        int ct = dd >> 11;
        int k = kc * 32 + ((L >> 4) << 3) + j;
        int n = ct * 16 + (L & 15);
        Wdst[dd] = __float2bfloat16(ldany(Wsrc, k * 128 + n, isf));
    }
}

// ---------------- CSR build ----------------

static __device__ __forceinline__ int load_dst(const int* ei, int e, int is32){
    if (e >= E0) return e - E0;
    return is32 ? ei[E0 + e] : (int)((const long long*)ei)[E0 + e];
}
static __device__ __forceinline__ int load_src(const int* ei, int e, int is32){
    if (e >= E0) return e - E0;
    return is32 ? ei[e] : (int)((const long long*)ei)[e];
}

__global__ void k_count(const int* __restrict__ ei, int* __restrict__ deg){
    int is32 = detect_i32(ei);
    int e = blockIdx.x * blockDim.x + threadIdx.x;
    if (e >= E_TOT) return;
    int dst = load_dst(ei, e, is32);
    int src = load_src(ei, e, is32);
    if ((unsigned)dst >= N_NODES || (unsigned)src >= N_NODES) return;
    atomicAdd(&deg[dst], 1);
}

__global__ void k_scanA(const int* __restrict__ deg, int* __restrict__ tmp, int* __restrict__ blk){
    __shared__ int s[256];
    int t = threadIdx.x;
    int i = blockIdx.x * 256 + t;
    int v = (i < N_NODES) ? deg[i] : 0;
    s[t] = v; __syncthreads();
    for (int off = 1; off < 256; off <<= 1){
        int x = (t >= off) ? s[t - off] : 0;
        __syncthreads();
        s[t] += x;
        __syncthreads();
    }
    if (t == 255) blk[blockIdx.x] = s[255];
    if (i < N_NODES) tmp[i] = s[t] - v;
}

__global__ void k_scanB(int* __restrict__ blk, int nb){
    __shared__ int s[256];
    int t = threadIdx.x;
    int v = (t < nb) ? blk[t] : 0;
    s[t] = v; __syncthreads();
    for (int off = 1; off < 256; off <<= 1){
        int x = (t >= off) ? s[t - off] : 0;
        __syncthreads();
        s[t] += x;
        __syncthreads();
    }
    if (t < nb) blk[t] = s[t] - v;
}

__global__ void k_scanC(int* __restrict__ row_ptr, const int* __restrict__ blk,
                        const int* __restrict__ deg, float* __restrict__ inv_sqrt){
    int i = blockIdx.x * blockDim.x + threadIdx.x;
    if (i < N_NODES){
        row_ptr[i] += blk[i >> 8];
        int d = deg[i];
        inv_sqrt[i] = (d > 0) ? rsqrtf((float)d) : 0.0f;
    }
    if (i == 0) row_ptr[N_NODES] = E_TOT;
}

__global__ void k_fill(const int* __restrict__ ei, const int* __restrict__ row_ptr,
                       const float* __restrict__ isq, int* __restrict__ cursor,
                       int* __restrict__ csr_src, float* __restrict__ coef){
    int is32 = detect_i32(ei);
    int e = blockIdx.x * blockDim.x + threadIdx.x;
    if (e >= E_TOT) return;
    int dst = load_dst(ei, e, is32);
    int src = load_src(ei, e, is32);
    if ((unsigned)dst >= N_NODES || (unsigned)src >= N_NODES) return;
    int pos = row_ptr[dst] + atomicAdd(&cursor[dst], 1);
    csr_src[pos] = src;
    coef[pos] = isq[dst] * isq[src];
}

// ---------------- gather: Xa = A_hat x — node-per-wave, ushort2/lane ----------------
__global__ __launch_bounds__(256, 2) void k_gather(
        const ushort2* __restrict__ xb2, const int* __restrict__ rp,
        const int* __restrict__ csr, const float* __restrict__ cf,
        unsigned* __restrict__ Xa){
    __shared__ int   scsr[SCAP];
    __shared__ float scf[SCAP];
    int n0 = blockIdx.x * 4;
    int b0 = rp[n0];
    int tot  = rp[n0 + 4] - b0;
    int stot = min(tot, SCAP);
    for (int i = threadIdx.x; i < stot; i += 256){
        scsr[i] = csr[b0 + i];
        scf[i]  = cf[b0 + i];
    }
    __syncthreads();

    int w = threadIdx.x >> 6, l = threadIdx.x & 63;
    int n = n0 + w;
    float a0 = 0.f, a1 = 0.f;
    int b = rp[n] - b0, e = rp[n + 1] - b0;
    int elim = min(e, stot);
    #pragma unroll 4
    for (int i = b; i < elim; ++i){
        int s = scsr[i];
        float c = scf[i];
        ushort2 v = xb2[(size_t)s * 64 + l];
        a0 += c * __uint_as_float((unsigned)v.x << 16);
        a1 += c * __uint_as_float((unsigned)v.y << 16);
    }
    for (int i = max(b, stot); i < e; ++i){    // fallback (pathological degree)
        int s = csr[b0 + i];
        float c = cf[b0 + i];
        ushort2 v = xb2[(size_t)s * 64 + l];
        a0 += c * __uint_as_float((unsigned)v.x << 16);
        a1 += c * __uint_as_float((unsigned)v.y << 16);
    }
    Xa[(size_t)n * 64 + l] = packbf(a0, a1);   // features 2l, 2l+1 (row-major, packed)
}

// ---------------- MFMA GEMM 128x128: O = A @ Wp [+b1,relu | interleave] ----------------
template<int EPI>
__global__ __launch_bounds__(512) void k_gemm_mfma(
        const bf16* __restrict__ A, const bf16* __restrict__ Wp,
        const float* __restrict__ vecf, bf16* __restrict__ O){
    int wid  = threadIdx.x >> 6;
    int lane = threadIdx.x & 63;
    int n0 = blockIdx.x * 16;
    int m = lane & 15, q = lane >> 4;

    const bfrag* Ap = (const bfrag*)(A + (size_t)(n0 + m) * 128);
    const bfrag* Bp = (const bfrag*)Wp + (size_t)wid * 256 + lane;

    ffrag c = {0.f, 0.f, 0.f, 0.f};
    #pragma unroll
    for (int kc = 0; kc < 4; ++kc){
        bfrag af = Ap[kc * 4 + q];
        bfrag bf = Bp[kc * 64];
        c = __builtin_amdgcn_mfma_f32_16x16x32_bf16(af, bf, c, 0, 0, 0);
    }
    __syncthreads();                      // all A reads done -> in-place stores safe

    int col = wid * 16 + m;
    if (EPI == 0){
        float bb = vecf[col];             // b1
        #pragma unroll
        for (int r = 0; r < 4; ++r){
            int row = n0 + q * 4 + r;
            O[(size_t)row * 128 + col] = __float2bfloat16(fmaxf(c[r] + bb, 0.f));
        }
    } else {                              // interleaved X2: slot (f*2 + head)
        int f = col & 63, h = col >> 6;
        #pragma unroll
        for (int r = 0; r < 4; ++r){
            int row = n0 + q * 4 + r;
            O[(size_t)row * 128 + f * 2 + h] = __float2bfloat16(c[r]);
        }
    }
}

// ---------------- MFMA GEMM 64x64: Z = Y @ W3p (bf16 out, no bias) ----------------
__global__ __launch_bounds__(256) void k_gemm_z(
        const bf16* __restrict__ Y, const bf16* __restrict__ W3p,
        bf16* __restrict__ Z){
    int wid  = threadIdx.x >> 6;
    int lane = threadIdx.x & 63;
    int n0 = blockIdx.x * 16;
    int m = lane & 15, q = lane >> 4;

    const bfrag* Ap = (const bfrag*)(Y + (size_t)(n0 + m) * 64);
    const bfrag* Bp = (const bfrag*)W3p + (size_t)wid * 128 + lane;

    ffrag c = {0.f, 0.f, 0.f, 0.f};
    #pragma unroll
    for (int kc = 0; kc < 2; ++kc){
        bfrag af = Ap[kc * 4 + q];
        bfrag bf = Bp[kc * 64];
        c = __builtin_amdgcn_mfma_f32_16x16x32_bf16(af, bf, c, 0, 0, 0);
    }
    int col = wid * 16 + m;
    #pragma unroll
    for (int r = 0; r < 4; ++r){
        int row = n0 + q * 4 + r;
        Z[(size_t)row * 64 + col] = __float2bfloat16(c[r]);
    }
}

// ---------------- att logits: per-node wave reduce over interleaved X2 ----------------
__global__ __launch_bounds__(256) void k_att(
        const unsigned* __restrict__ X2u, const float* __restrict__ vecf,
        float2* __restrict__ a_src, float2* __restrict__ a_dst){
    int n = blockIdx.x * 4 + (threadIdx.x >> 6);
    int l = threadIdx.x & 63;
    unsigned v = X2u[(size_t)n * 64 + l];
    float x0 = bfu2f_lo(v), x1 = bfu2f_hi(v);
    float s0 = x0 * vecf[256 + l], s1 = x1 * vecf[320 + l];
    float d0 = x0 * vecf[384 + l], d1 = x1 * vecf[448 + l];
    for (int off = 32; off; off >>= 1){
        s0 += __shfl_down(s0, off, 64);  s1 += __shfl_down(s1, off, 64);
        d0 += __shfl_down(d0, off, 64);  d1 += __shfl_down(d1, off, 64);
    }
    if (l == 0){
        a_src[n] = make_float2(s0, s1);
        a_dst[n] = make_float2(d0, d1);
    }
}

// ---------------- GAT aggregate: two-phase (per-edge exp once, then feature FMA) ----------
// Phase A: lanes compute p = exp(leaky(logit)) for DISTINCT edges of the wave's node
// (lane-strided) -> LDS. Phase B: feature loop reads pe[i] as an LDS broadcast; per-edge
// per-lane work drops to unpack + 4 FMA. Waves touch disjoint pe ranges (no extra barrier).
__global__ __launch_bounds__(256) void k_gat(
        const unsigned* __restrict__ X2u, const int* __restrict__ rp,
        const int* __restrict__ csr, const float2* __restrict__ a_src,
        const float2* __restrict__ a_dst, const float* __restrict__ vecf,
        bf16* __restrict__ Y){
    __shared__ int    scsr[SCAP];
    __shared__ float2 pe[SCAP];
    int n0 = blockIdx.x * 4;
    int b0 = rp[n0];
    int tot  = rp[n0 + 4] - b0;
    int stot = min(tot, SCAP);
    for (int i = threadIdx.x; i < stot; i += 256) scsr[i] = csr[b0 + i];
    __syncthreads();

    int w = threadIdx.x >> 6, f = threadIdx.x & 63;
    int n = n0 + w;
    float2 ad = a_dst[n];
    int b = rp[n] - b0, e = rp[n + 1] - b0;
    int elim = min(e, stot);

    // Phase A: per-edge softmax numerators, one lane per edge
    for (int i = b + f; i < elim; i += 64){
        float2 av = a_src[scsr[i]];
        float e0 = av.x + ad.x, e1 = av.y + ad.y;
        e0 = (e0 > 0.f) ? e0 : 0.2f * e0;              // leaky_relu 0.2
        e1 = (e1 > 0.f) ? e1 : 0.2f * e1;
        pe[i] = make_float2(__expf(e0), __expf(e1));
    }
    // intra-wave LDS write->read; compiler inserts lgkmcnt wait (same LDS object)

    // Phase B: feature accumulation (pe[i]/scsr[i] are wave-uniform LDS broadcasts)
    float l0 = 0.f, l1 = 0.f, o0 = 0.f, o1 = 0.f;
    #pragma unroll 4
    for (int i = b; i < elim; ++i){
        float2 p = pe[i];
        unsigned v = X2u[(size_t)scsr[i] * 64 + f];
        l0 += p.x;  o0 += p.x * bfu2f_lo(v);
        l1 += p.y;  o1 += p.y * bfu2f_hi(v);
    }
    for (int i = max(b, stot); i < e; ++i){            // fallback (pathological degree)
        int s = csr[b0 + i];
        float2 av = a_src[s];
        unsigned v = X2u[(size_t)s * 64 + f];
        float e0 = av.x + ad.x, e1 = av.y + ad.y;
        e0 = (e0 > 0.f) ? e0 : 0.2f * e0;
        e1 = (e1 > 0.f) ? e1 : 0.2f * e1;
        float p0 = __expf(e0), p1 = __expf(e1);
        l0 += p0;  o0 += p0 * bfu2f_lo(v);
        l1 += p1;  o1 += p1 * bfu2f_hi(v);
    }
    float val = 0.5f * (o0 / l0 + o1 / l1) + vecf[128 + f];  // bg (self-loop => l>0)
    val = (val > 0.f) ? val : expm1f(val);                    // ELU alpha=1
    Y[(size_t)n * 64 + f] = __float2bfloat16(val);
}

// ---------------- gather_out: out = A_hat Z + b3 (fp32 out) ----------------
__global__ __launch_bounds__(256) void k_gather_out(
        const bf16* __restrict__ Z, const int* __restrict__ rp,
        const int* __restrict__ csr, const float* __restrict__ cf,
        const float* __restrict__ vecf, float* __restrict__ out){
    __shared__ int   scsr[SCAP];
    __shared__ float scf[SCAP];
    int n0 = blockIdx.x * 4;
    int b0 = rp[n0];
    int tot  = rp[n0 + 4] - b0;
    int stot = min(tot, SCAP);
    for (int i = threadIdx.x; i < stot; i += 256){
        scsr[i] = csr[b0 + i];
        scf[i]  = cf[b0 + i];
    }
    __syncthreads();

    int w = threadIdx.x >> 6, f = threadIdx.x & 63;
    int n = n0 + w;
    float a = vecf[192 + f];                   // b3
    int b = rp[n] - b0, e = rp[n + 1] - b0;
    int elim = min(e, stot);
    #pragma unroll 4
    for (int i = b; i < elim; ++i)
        a += scf[i] * __bfloat162float(Z[(size_t)scsr[i] * 64 + f]);
    for (int i = max(b, stot); i < e; ++i)     // fallback
        a += cf[b0 + i] * __bfloat162float(Z[(size_t)csr[b0 + i] * 64 + f]);
    out[(size_t)n * 64 + f] = a;
}

// ---------------- launch ----------------

extern "C" void kernel_launch(void* const* d_in, const int* in_sizes, int n_in,
                              void* d_out, int out_size, void* d_ws, size_t ws_size,
                              hipStream_t stream) {
    const void* x  = d_in[0];
    const int*  ei = (const int*)d_in[1];
    float* out = (float*)d_out;

    char* p = (char*)d_ws;
    auto alloc = [&](size_t bytes) -> void* {
        void* r = (void*)p;
        p += (bytes + 255) & ~(size_t)255;
        return r;
    };
    int*   deg      = (int*)  alloc((size_t)N_NODES * 4);
    int*   cursor   = (int*)  alloc((size_t)N_NODES * 4);
    int*   row_ptr  = (int*)  alloc((size_t)(N_NODES + 1) * 4);
    int*   blk      = (int*)  alloc(256 * 4);
    int*   csr      = (int*)  alloc((size_t)E_TOT * 4);
    float* coef     = (float*)alloc((size_t)E_TOT * 4);
    float* inv_sqrt = (float*)alloc((size_t)N_NODES * 4);
    float* a_src    = (float*)alloc((size_t)N_NODES * 2 * 4);
    float* a_dst    = (float*)alloc((size_t)N_NODES * 2 * 4);
    bf16*  W1p      = (bf16*) alloc(16384 * 2);
    bf16*  Wgp      = (bf16*) alloc(16384 * 2);
    bf16*  W3p      = (bf16*) alloc(4096 * 2);
    float* vecf     = (float*)alloc(512 * 4);
    bf16*  xb       = (bf16*) alloc((size_t)N_NODES * 128 * 2);  // 12.8 MB; dead after k_gather
    bf16*  XA       = (bf16*) alloc((size_t)N_NODES * 128 * 2);  // 12.8 MB (Xa -> h1 -> X2)
    bf16*  Y        = (bf16*) alloc((size_t)N_NODES * 64 * 2);   //  6.4 MB
    bf16*  Z        = xb;                                        // alias: Y@W3, layer-3 only
    // total ~40 MB

    const int NB_NODE = (N_NODES + 255) / 256;              // 196
    const int NB_EDGE = (E_TOT + 255) / 256;
    const int NXB     = (N_NODES * 128 + 255) / 256;
    const int NB_CONV = 148 + NXB + NB_NODE;

    k_convert<<<NB_CONV, 256, 0, stream>>>(x, d_in[2], d_in[4], d_in[8],
                                           d_in[3], d_in[7], d_in[9], d_in[5], d_in[6],
                                           W1p, Wgp, W3p, vecf, xb, deg, cursor);
    k_count<<<NB_EDGE, 256, 0, stream>>>(ei, deg);
    k_scanA<<<NB_NODE, 256, 0, stream>>>(deg, row_ptr, blk);
    k_scanB<<<1, 256, 0, stream>>>(blk, NB_NODE);
    k_scanC<<<NB_NODE, 256, 0, stream>>>(row_ptr, blk, deg, inv_sqrt);
    k_fill<<<NB_EDGE, 256, 0, stream>>>(ei, row_ptr, inv_sqrt, cursor, csr, coef);

    k_gather<<<N_NODES / 4, 256, 0, stream>>>((const ushort2*)xb, row_ptr, csr, coef,
                                              (unsigned*)XA);
    k_gemm_mfma<0><<<N_NODES / 16, 512, 0, stream>>>(XA, W1p, vecf, XA);   // h1 = relu(Xa W1 + b1)
    k_gemm_mfma<1><<<N_NODES / 16, 512, 0, stream>>>(XA, Wgp, vecf, XA);   // X2 = h1 Wg (interleaved)
    k_att<<<N_NODES / 4, 256, 0, stream>>>((const unsigned*)XA, vecf, (float2*)a_src, (float2*)a_dst);
    k_gat<<<N_NODES / 4, 256, 0, stream>>>((const unsigned*)XA, row_ptr, csr,
                                           (const float2*)a_src, (const float2*)a_dst,
                                           vecf, Y);
    k_gemm_z<<<N_NODES / 16, 256, 0, stream>>>(Y, W3p, Z);                 // Z = Y W3
    k_gather_out<<<N_NODES / 4, 256, 0, stream>>>(Z, row_ptr, csr, coef, vecf, out);
}